// Round 1
// baseline (587.187 us; speedup 1.0000x reference)
//
#include <hip/hip_runtime.h>
#include <hip/hip_bf16.h>

// Problem constants (fixed by setup_inputs)
#define T_TOK 4096   // B*S = 4*1024
#define HD    1024   // hidden
#define FD    2048   // ffn
#define NEXP  8
#define NSH   2

using u16 = unsigned short;
typedef __bf16 bf16x8 __attribute__((ext_vector_type(8)));
typedef float  f32x4  __attribute__((ext_vector_type(4)));
typedef u16    u16x2  __attribute__((ext_vector_type(2)));
typedef u16    u16x4  __attribute__((ext_vector_type(4)));

__device__ __forceinline__ u16 f2bf(float f) {
    __hip_bfloat16 h = __float2bfloat16(f);   // RNE
    u16 u; __builtin_memcpy(&u, &h, 2);
    return u;
}

// async global->LDS, 16B per lane. HW: wave-uniform base + lane*16B.
__device__ __forceinline__ void gl2lds16(const u16* g, u16* l) {
    __builtin_amdgcn_global_load_lds((__attribute__((address_space(1))) void*)(g),
                                     (__attribute__((address_space(3))) void*)(l),
                                     16, 0, 0);
}

// tanh-form GELU: max abs err ~1e-3 vs exact erf form — negligible after W2.
__device__ __forceinline__ float gelu_fast(float v) {
    float u = v * (0.7978845608028654f + 0.035677408136300125f * v * v);
    return v * __builtin_amdgcn_rcpf(1.0f + __expf(-2.0f * u));
}

// ---------------------------------------------------------------------------
// 256x256 tile, BK=64, 8 waves (2x4), 8-phase schedule (T2+T3+T4+T5).
// LDS: 2 bufs x (A 256x64 + B 256x64) bf16 = 128 KiB.
// Swizzle: logical 16B-chunk c at tile-row r lives at physical chunk
//   c ^ ((r>>1)&7). Write side: pre-swizzled GLOBAL source (global_load_lds
//   dest stays linear, m104/m173); read side: same XOR on ds_read addr.
//   => every 16-lane fragment read is exactly 2-way per bank (free, m136).
// Staging: half-tile (128 rows x 128B) = 2 x global_load_lds_dwordx4 per
//   thread; one half-tile issued per phase, lead 6 half-tiles; boundary wait
//   s_waitcnt vmcnt(4) (never 0 in steady state).
// ---------------------------------------------------------------------------
template<int Q>   // Q: 0,1 = A halves; 2,3 = B halves
__device__ __forceinline__ void stage_q(const u16* const rb[8], u16* S,
                                        int bufsel, int ktile, int nT) {
    if (ktile >= nT) return;                    // uniform
    constexpr int isB = Q >> 1, half = Q & 1;
    u16* dst = S + (bufsel * 2 + isB) * 16384 + half * 8192 + threadIdx.x * 8;
    constexpr int base = isB * 4 + half * 2;
    gl2lds16(rb[base + 0] + (size_t)ktile * 64, dst);
    gl2lds16(rb[base + 1] + (size_t)ktile * 64, dst + 4096);
}

__device__ __forceinline__ void core256(const u16* const rb[8], u16* S,
                                        int nT, f32x4 acc[8][4]) {
    const int tid = threadIdx.x, wave = tid >> 6, lane = tid & 63;
    const int wm = wave >> 2, wn = wave & 3;
    const int l16 = lane & 15, quad = lane >> 4;
    const int xr = l16 >> 1;                    // read-side swizzle term
    // prologue: tile0 {A0,A1,B0,B1}, tile1 {A0,A1}  (ht 0..5)
    stage_q<0>(rb, S, 0, 0, nT); stage_q<1>(rb, S, 0, 0, nT);
    stage_q<2>(rb, S, 0, 0, nT); stage_q<3>(rb, S, 0, 0, nT);
    stage_q<0>(rb, S, 1, 1, nT); stage_q<1>(rb, S, 1, 1, nT);
    asm volatile("s_waitcnt vmcnt(4)" ::: "memory");   // tile0 complete
    __builtin_amdgcn_s_barrier();
    __builtin_amdgcn_sched_barrier(0);
    for (int t = 0; t < nT; ++t) {
        const int cur = t & 1;
        const u16* At = S + cur * 32768;
        const u16* Bt = At + 16384;
        const u16* Arow = At + (wm * 128 + l16) * 64;
        const u16* Brow = Bt + (wn * 64 + l16) * 64;
        bf16x8 a0[8], b0[4], a1[8], b1[4];
        // ---- P0: read A k0 (8) + B k0 (4); stage (t+1, B-h0)
#pragma unroll
        for (int i = 0; i < 8; ++i)
            a0[i] = *(const bf16x8*)(Arow + i * 1024 + ((quad ^ xr) * 8));
#pragma unroll
        for (int j = 0; j < 4; ++j)
            b0[j] = *(const bf16x8*)(Brow + j * 1024 + ((quad ^ xr) * 8));
        stage_q<2>(rb, S, cur ^ 1, t + 1, nT);
        __builtin_amdgcn_s_barrier();
        asm volatile("s_waitcnt lgkmcnt(0)" ::: "memory");
        __builtin_amdgcn_sched_barrier(0);
        __builtin_amdgcn_s_setprio(1);
#pragma unroll
        for (int i = 0; i < 4; ++i)
#pragma unroll
            for (int j = 0; j < 4; ++j)
                acc[i][j] = __builtin_amdgcn_mfma_f32_16x16x32_bf16(a0[i], b0[j], acc[i][j], 0, 0, 0);
        __builtin_amdgcn_s_setprio(0);
        __builtin_amdgcn_s_barrier();
        // ---- P1: read A k1 (8); stage (t+1, B-h1)
#pragma unroll
        for (int i = 0; i < 8; ++i)
            a1[i] = *(const bf16x8*)(Arow + i * 1024 + (((4 + quad) ^ xr) * 8));
        stage_q<3>(rb, S, cur ^ 1, t + 1, nT);
        __builtin_amdgcn_s_barrier();
        asm volatile("s_waitcnt lgkmcnt(0)" ::: "memory");
        __builtin_amdgcn_sched_barrier(0);
        __builtin_amdgcn_s_setprio(1);
#pragma unroll
        for (int i = 0; i < 4; ++i)
#pragma unroll
            for (int j = 0; j < 4; ++j)
                acc[4 + i][j] = __builtin_amdgcn_mfma_f32_16x16x32_bf16(a0[4 + i], b0[j], acc[4 + i][j], 0, 0, 0);
        __builtin_amdgcn_s_setprio(0);
        __builtin_amdgcn_s_barrier();
        // ---- P2: read B k1 (4); stage (t+2, A-h0) — all A reads of this
        //      tile completed at P1 (lgkmcnt(0)) + P1-end barrier => safe.
#pragma unroll
        for (int j = 0; j < 4; ++j)
            b1[j] = *(const bf16x8*)(Brow + j * 1024 + (((4 + quad) ^ xr) * 8));
        stage_q<0>(rb, S, cur, t + 2, nT);
        __builtin_amdgcn_s_barrier();
        asm volatile("s_waitcnt lgkmcnt(0)" ::: "memory");
        __builtin_amdgcn_sched_barrier(0);
        __builtin_amdgcn_s_setprio(1);
#pragma unroll
        for (int i = 0; i < 4; ++i)
#pragma unroll
            for (int j = 0; j < 4; ++j)
                acc[i][j] = __builtin_amdgcn_mfma_f32_16x16x32_bf16(a1[i], b1[j], acc[i][j], 0, 0, 0);
        __builtin_amdgcn_s_setprio(0);
        __builtin_amdgcn_s_barrier();
        // ---- P3: stage (t+2, A-h1); MFMA; K-tile boundary wait (counted)
        stage_q<1>(rb, S, cur, t + 2, nT);
        __builtin_amdgcn_s_barrier();
        __builtin_amdgcn_s_setprio(1);
#pragma unroll
        for (int i = 0; i < 4; ++i)
#pragma unroll
            for (int j = 0; j < 4; ++j)
                acc[4 + i][j] = __builtin_amdgcn_mfma_f32_16x16x32_bf16(a1[4 + i], b1[j], acc[4 + i][j], 0, 0, 0);
        __builtin_amdgcn_s_setprio(0);
        if (t < nT - 2)       asm volatile("s_waitcnt vmcnt(4)" ::: "memory");
        else if (t == nT - 2) asm volatile("s_waitcnt vmcnt(0)" ::: "memory");
        __builtin_amdgcn_s_barrier();
        __builtin_amdgcn_sched_barrier(0);
    }
}

// ---------------------------------------------------------------------------
// Coalesced bf16 epilogue (per-wave private LDS region; proven pattern).
// Wave tile is 128x64: 8 i-blocks of 16 rows x 64 cols. Row guard for
// routed tails.
// ---------------------------------------------------------------------------
#define EPI_STRIDE 68
template<bool GELU>
__device__ __forceinline__ void epi_bf16_w(
    f32x4 acc[8][4], const float bj[4],
    u16* __restrict__ dst, size_t ld, int row0, int colbase, int rowmax, u16* lds)
{
    const int lane = threadIdx.x & 63;
    const int l16 = lane & 15, quad = lane >> 4;
    const int rr = lane >> 2, seg = lane & 3;
#pragma unroll
    for (int i = 0; i < 8; ++i) {
#pragma unroll
        for (int j = 0; j < 4; ++j)
#pragma unroll
            for (int r = 0; r < 4; ++r) {
                float v = acc[i][j][r] + bj[j];
                if (GELU) v = gelu_fast(v);
                lds[(quad * 4 + r) * EPI_STRIDE + j * 16 + l16] = f2bf(v);
            }
        asm volatile("s_waitcnt lgkmcnt(0)" ::: "memory");
        const int grow = row0 + i * 16 + rr;
        if (grow < rowmax) {
            const u16* lp = lds + rr * EPI_STRIDE + seg * 16;
            u16x4 v0 = *(const u16x4*)(lp);
            u16x4 v1 = *(const u16x4*)(lp + 4);
            u16x4 v2 = *(const u16x4*)(lp + 8);
            u16x4 v3 = *(const u16x4*)(lp + 12);
            u16* gp = dst + (size_t)grow * ld + colbase + seg * 16;
            *(u16x4*)(gp)      = v0;
            *(u16x4*)(gp + 4)  = v1;
            *(u16x4*)(gp + 8)  = v2;
            *(u16x4*)(gp + 12) = v3;
        }
        asm volatile("s_waitcnt lgkmcnt(0)" ::: "memory");  // drain before next i
    }
}

// XCD-chunked (T1) bijective swizzle of the (nt,mt) plane, rotated by z so
// routed planes' few active mt-tiles spread across XCDs. NWG % 8 == 0.
template<int NX, int NWG>
__device__ __forceinline__ void xcd_map(int z, int& nt, int& mt) {
    const int flat = blockIdx.x + NX * blockIdx.y;
    constexpr int q = NWG >> 3;
    const int xcd = (flat - z) & 7;
    const int s = xcd * q + (flat >> 3);
    nt = s % NX;
    mt = s / NX;
}

// ---------------------------------------------------------------------------
// Fused convert + router: writes xb (bf16) and per-expert token lists.
// ---------------------------------------------------------------------------
__global__ __launch_bounds__(256) void router_convert_kernel(
    const float* __restrict__ x, const float* __restrict__ rw, const float* __restrict__ rb,
    u16* __restrict__ xb, int* __restrict__ cnt, int* __restrict__ lists)
{
    const int t = blockIdx.x * 4 + (threadIdx.x >> 6);
    const int lane = threadIdx.x & 63;
    const float* xr = x + (size_t)t * HD;
    u16* xbr = xb + (size_t)t * HD;
    float acc[NEXP];
#pragma unroll
    for (int e = 0; e < NEXP; ++e) acc[e] = 0.f;
#pragma unroll
    for (int it = 0; it < 4; ++it) {
        int h0 = it * 256 + lane * 4;
        float4 v = *(const float4*)(xr + h0);
        ushort4 o = { f2bf(v.x), f2bf(v.y), f2bf(v.z), f2bf(v.w) };
        *(ushort4*)(xbr + h0) = o;
        float xv[4] = { v.x, v.y, v.z, v.w };
#pragma unroll
        for (int q = 0; q < 4; ++q) {
            const float4* wp = (const float4*)(rw + (size_t)(h0 + q) * NEXP);
            float4 w0 = wp[0], w1 = wp[1];
            acc[0] += xv[q] * w0.x; acc[1] += xv[q] * w0.y;
            acc[2] += xv[q] * w0.z; acc[3] += xv[q] * w0.w;
            acc[4] += xv[q] * w1.x; acc[5] += xv[q] * w1.y;
            acc[6] += xv[q] * w1.z; acc[7] += xv[q] * w1.w;
        }
    }
#pragma unroll
    for (int e = 0; e < NEXP; ++e)
        for (int off = 32; off; off >>= 1) acc[e] += __shfl_xor(acc[e], off, 64);
    if (lane == 0) {
#pragma unroll
        for (int e = 0; e < NEXP; ++e) acc[e] += rb[e];
        int b1i = 0;
        for (int e = 1; e < NEXP; ++e) if (acc[e] > acc[b1i]) b1i = e;
        int b2i = (b1i == 0) ? 1 : 0;
        for (int e = 0; e < NEXP; ++e) if (e != b1i && acc[e] > acc[b2i]) b2i = e;
        int p1 = atomicAdd(&cnt[b1i], 1); lists[b1i * T_TOK + p1] = t;
        int p2 = atomicAdd(&cnt[b2i], 1); lists[b2i * T_TOK + p2] = t;
    }
}

__global__ void offsets_kernel(const int* __restrict__ cnt, int* __restrict__ pfx) {
    if (threadIdx.x == 0 && blockIdx.x == 0) {
        int s = 0;
        for (int e = 0; e < NEXP; ++e) { pfx[e] = s; s += ((cnt[e] + 127) >> 7) << 7; }
        pfx[NEXP] = s;
    }
}

// ---------------------------------------------------------------------------
// Transposes: fp32 [K,N] -> bf16 [N,K]. 64(dst-contig) x 32 tiles.
// ---------------------------------------------------------------------------
__global__ __launch_bounds__(256) void transpose_w1_kernel(
    const float* __restrict__ sw1, const float* __restrict__ ew1, u16* __restrict__ wt)
{
    __shared__ u16 tile[32][65];
    const int z = blockIdx.z;
    const float* src = (z < NSH) ? (sw1 + (size_t)z * HD * FD)
                                 : (ew1 + (size_t)(z - NSH) * HD * FD);
    u16* dst = wt + (size_t)z * FD * HD;           // [f][h], ld = HD
    const int tx = threadIdx.x, ty = threadIdx.y;  // (32, 8)
    const int c0 = blockIdx.x * 32;                // over FD (dst rows)
    const int r0 = blockIdx.y * 64;                // over HD (dst contig)
#pragma unroll
    for (int k = 0; k < 8; ++k)
        tile[tx][ty + 8 * k] = f2bf(src[(size_t)(r0 + ty + 8 * k) * FD + c0 + tx]);
    __syncthreads();
#pragma unroll
    for (int k = 0; k < 4; ++k) {
        int c = ty + 8 * k;
        u16x2 v = { tile[c][2 * tx], tile[c][2 * tx + 1] };
        *(u16x2*)(dst + (size_t)(c0 + c) * HD + r0 + 2 * tx) = v;
    }
}

// shared_w2[s][f][h] -> w2tS[h][s*FD+f] (ld=2FD);  exp_w2[e][f][h] -> [e][h][f]
__global__ __launch_bounds__(256) void transpose_w2_kernel(
    const float* __restrict__ sw2, const float* __restrict__ ew2, u16* __restrict__ wt)
{
    __shared__ u16 tile[32][65];
    const int z = blockIdx.z;
    const float* src; u16* dst; size_t ldd;
    if (z < NSH) { src = sw2 + (size_t)z * FD * HD; dst = wt + (size_t)z * FD; ldd = 2 * FD; }
    else { src = ew2 + (size_t)(z - NSH) * FD * HD;
           dst = wt + (size_t)NSH * FD * HD + (size_t)(z - NSH) * HD * FD; ldd = FD; }
    const int tx = threadIdx.x, ty = threadIdx.y;  // (32, 8)
    const int c0 = blockIdx.x * 32;                // over HD (dst rows h)
    const int r0 = blockIdx.y * 64;                // over FD (dst contig f)
#pragma unroll
    for (int k = 0; k < 8; ++k)
        tile[tx][ty + 8 * k] = f2bf(src[(size_t)(r0 + ty + 8 * k) * HD + c0 + tx]);
    __syncthreads();
#pragma unroll
    for (int k = 0; k < 4; ++k) {
        int c = ty + 8 * k;
        u16x2 v = { tile[c][2 * tx], tile[c][2 * tx + 1] };
        *(u16x2*)(dst + (size_t)(c0 + c) * ldd + r0 + 2 * tx) = v;
    }
}

// ---------------------------------------------------------------------------
// GEMM1 (K=1024, 16 K-tiles): z<NSH -> shared expert s=z (hidS[t][s*FD+f]);
// z>=NSH -> routed expert e=z-NSH (hidE[pfx[e]+slot][f]), tokens gathered
// via lists (zero-padded -> token 0 for tail rows; finite, masked later).
// ---------------------------------------------------------------------------
__global__ __launch_bounds__(512, 2) void gemm1_all_256(
    const u16* __restrict__ xb, const u16* __restrict__ w1t,
    const float* __restrict__ sb1, const float* __restrict__ eb1,
    const int* __restrict__ cnt, const int* __restrict__ pfx,
    const int* __restrict__ lists,
    u16* __restrict__ hidS, u16* __restrict__ hidE)
{
    const int z = blockIdx.z;
    int nt, mt; xcd_map<FD / 256, (FD / 256) * (T_TOK / 256)>(z, nt, mt);
    const bool routed = (z >= NSH);
    const int e = z - NSH;
    int ce = 0, pe = 0;
    if (routed) { ce = cnt[e]; pe = pfx[e]; if (mt * 256 >= ce) return; }
    __shared__ __align__(16) u16 S[4 * 16384];     // 128 KiB
    const int tid = threadIdx.x;
    const int u = tid >> 3;
    const int cl = (tid & 7) ^ ((tid >> 4) & 7);   // pre-swizzled source chunk
    const u16* rb[8];
    if (routed) {
#pragma unroll
        for (int q = 0; q < 4; ++q) {
            const int tok = lists[e * T_TOK + mt * 256 + q * 64 + u];
            rb[q] = xb + (size_t)tok * HD + cl * 8;
        }
    } else {
#pragma unroll
        for (int q = 0; q < 4; ++q)
            rb[q] = xb + (size_t)(mt * 256 + q * 64 + u) * HD + cl * 8;
    }
    const u16* wb = w1t + (size_t)z * FD * HD + (size_t)(nt * 256 + u) * HD + cl * 8;
#pragma unroll
    for (int q = 0; q < 4; ++q) rb[4 + q] = wb + (size_t)(q * 64) * HD;

    f32x4 acc[8][4] = {};
    core256(rb, S, HD / 64, acc);

    const int wave = tid >> 6, lane = tid & 63;
    const int wm = wave >> 2, wn = wave & 3, l16 = lane & 15;
    const float* bias = routed ? (eb1 + e * FD) : (sb1 + z * FD);
    float bj[4];
#pragma unroll
    for (int j = 0; j < 4; ++j) bj[j] = bias[nt * 256 + wn * 64 + j * 16 + l16];
    u16* dst = routed ? hidE : hidS;
    const size_t ld = routed ? FD : 2 * FD;
    const int colbase = (routed ? 0 : z * FD) + nt * 256 + wn * 64;
    const int row0 = (routed ? pe : 0) + mt * 256 + wm * 128;
    const int rowmax = routed ? (pe + ((ce + 127) & ~127)) : (1 << 30);
    epi_bf16_w<true>(acc, bj, dst, ld, row0, colbase, rowmax, S + wave * 16 * EPI_STRIDE);
}

// ---------------------------------------------------------------------------
// GEMM2, all planes K=1024 for uniform block cost (no straggler tail):
//   z in [0,4):  shared expert s=z>>1, K-half kh=z&1, rows direct.
//   z in [4,20): routed expert e=(z-4)>>1, K-half kh, rows scattered to
//                out[token] via lists.
// All planes accumulate with fp32 atomicAdd into zeroed `out` (device-scope,
// XCD-safe). Replaces routedOut + finalize entirely.
// ---------------------------------------------------------------------------
__global__ __launch_bounds__(512, 2) void gemm2_all_256(
    const u16* __restrict__ hidS, const u16* __restrict__ hidE,
    const u16* __restrict__ w2t,
    const float* __restrict__ sb2, const float* __restrict__ eb2,
    const int* __restrict__ cnt, const int* __restrict__ pfx,
    const int* __restrict__ lists,
    float* __restrict__ out)
{
    const int z = blockIdx.z;
    int nt, mt; xcd_map<HD / 256, (HD / 256) * (T_TOK / 256)>(z, nt, mt);
    const bool sharedp = (z < 2 * NSH);
    const int e = (z - 2 * NSH) >> 1;
    const int kh = sharedp ? (z & 1) : ((z - 2 * NSH) & 1);
    int ce = 0, pe = 0;
    if (!sharedp) { ce = cnt[e]; pe = pfx[e]; if (mt * 256 >= ce) return; }
    __shared__ __align__(16) u16 S[4 * 16384];
    const int tid = threadIdx.x;
    const int u = tid >> 3;
    const int cl = (tid & 7) ^ ((tid >> 4) & 7);
    const u16* rb[8];
    if (sharedp) {
        const int s = z >> 1;
        const u16* ab = hidS + (size_t)s * FD + (size_t)kh * (FD / 2) + cl * 8;
        const u16* bb = w2t + (size_t)s * FD + (size_t)kh * (FD / 2) + cl * 8;
#pragma unroll
        for (int q = 0; q < 4; ++q) {
            rb[q]     = ab + (size_t)(mt * 256 + q * 64 + u) * (2 * FD);
            rb[4 + q] = bb + (size_t)(nt * 256 + q * 64 + u) * (2 * FD);
        }
    } else {
        const u16* ab = hidE + (size_t)(pe + mt * 256 + u) * FD + (size_t)kh * (FD / 2) + cl * 8;
        const u16* bb = w2t + (size_t)NSH * FD * HD + (size_t)e * HD * FD
                      + (size_t)(nt * 256 + u) * FD + (size_t)kh * (FD / 2) + cl * 8;
#pragma unroll
        for (int q = 0; q < 4; ++q) {
            rb[q]     = ab + (size_t)(q * 64) * FD;
            rb[4 + q] = bb + (size_t)(q * 64) * FD;
        }
    }
    f32x4 acc[8][4] = {};
    core256(rb, S, (FD / 2) / 64, acc);   // 16 K-tiles

    const int wave = tid >> 6, lane = tid & 63;
    const int wm = wave >> 2, wn = wave & 3, l16 = lane & 15, quad = lane >> 4;
    float bj[4];
#pragma unroll
    for (int j = 0; j < 4; ++j) {
        const int h = nt * 256 + wn * 64 + j * 16 + l16;
        float bv = 0.0f;
        if (sharedp) { if (z == 0) bv = sb2[h] + sb2[HD + h]; }   // both shared biases once
        else if (kh == 0) bv = eb2[e * HD + h];                   // expert bias once
        bj[j] = bv;
    }
    const int cb = nt * 256 + wn * 64 + l16;
    if (sharedp) {
#pragma unroll
        for (int i = 0; i < 8; ++i) {
            const int row = mt * 256 + wm * 128 + i * 16 + quad * 4;
#pragma unroll
            for (int r = 0; r < 4; ++r) {
                float* po = out + (size_t)(row + r) * HD + cb;
#pragma unroll
                for (int j = 0; j < 4; ++j)
                    atomicAdd(po + j * 16, acc[i][j][r] + bj[j]);
            }
        }
    } else {
#pragma unroll
        for (int i = 0; i < 8; ++i) {
            const int rloc = mt * 256 + wm * 128 + i * 16 + quad * 4;
#pragma unroll
            for (int r = 0; r < 4; ++r) {
                if (rloc + r < ce) {
                    const int tok = lists[e * T_TOK + rloc + r];
                    float* po = out + (size_t)tok * HD + cb;
#pragma unroll
                    for (int j = 0; j < 4; ++j)
                        atomicAdd(po + j * 16, acc[i][j][r] + bj[j]);
                }
            }
        }
    }
}

// ---------------------------------------------------------------------------
// Workspace layout (bytes) — single path, fits the proven-safe size:
//   wt    @ 0           : 41,943,040  (w1^T, later reused for w2^T)
//   hidS  @ 41,943,040  : 33,554,432  (bf16 [4096][2*FD])
//   hidE  @ 75,497,472  : 37,748,736  (bf16 [9216][FD])
//   xb    @ 113,246,208 :  8,388,608
//   smalls@ 121,634,816 : cnt 64 | pfx 64 | lists 131072  -> end 121,766,016
// ---------------------------------------------------------------------------
extern "C" void kernel_launch(void* const* d_in, const int* in_sizes, int n_in,
                              void* d_out, int out_size, void* d_ws, size_t ws_size,
                              hipStream_t stream)
{
    (void)in_sizes; (void)n_in; (void)out_size; (void)ws_size;
    const float* x   = (const float*)d_in[0];
    const float* sw1 = (const float*)d_in[1];
    const float* sb1 = (const float*)d_in[2];
    const float* sw2 = (const float*)d_in[3];
    const float* sb2 = (const float*)d_in[4];
    const float* ew1 = (const float*)d_in[5];
    const float* eb1 = (const float*)d_in[6];
    const float* ew2 = (const float*)d_in[7];
    const float* eb2 = (const float*)d_in[8];
    const float* rw  = (const float*)d_in[9];
    const float* rb  = (const float*)d_in[10];
    float* out = (float*)d_out;

    char* ws   = (char*)d_ws;
    u16*  wt   = (u16*)ws;
    u16*  hidS = (u16*)(ws + 41943040);
    u16*  hidE = (u16*)(ws + 75497472);
    u16*  xb   = (u16*)(ws + 113246208);
    int*  cnt   = (int*)(ws + 121634816);
    int*  pfx   = (int*)(ws + 121634816 + 64);
    int*  lists = (int*)(ws + 121634816 + 128);

    hipMemsetAsync(cnt, 0, 128 + (size_t)NEXP * T_TOK * 4, stream);  // cnt+pfx+lists
    hipMemsetAsync(out, 0, (size_t)T_TOK * HD * 4, stream);          // atomic target

    router_convert_kernel<<<dim3(T_TOK / 4), dim3(256), 0, stream>>>(x, rw, rb, xb, cnt, lists);
    offsets_kernel<<<dim3(1), dim3(64), 0, stream>>>(cnt, pfx);
    transpose_w1_kernel<<<dim3(FD / 32, HD / 64, NSH + NEXP), dim3(32, 8), 0, stream>>>(sw1, ew1, wt);

    gemm1_all_256<<<dim3(FD / 256, T_TOK / 256, NSH + NEXP), dim3(512), 0, stream>>>(
        xb, wt, sb1, eb1, cnt, pfx, lists, hidS, hidE);

    transpose_w2_kernel<<<dim3(HD / 32, FD / 64, NSH + NEXP), dim3(32, 8), 0, stream>>>(sw2, ew2, wt);

    gemm2_all_256<<<dim3(HD / 256, T_TOK / 256, 2 * NSH + 2 * NEXP), dim3(512), 0, stream>>>(
        hidS, hidE, wt, sb2, eb2, cnt, pfx, lists, out);
}

// Round 2
// 530.471 us; speedup vs baseline: 1.1069x; 1.1069x over previous
//
#include <hip/hip_runtime.h>
#include <hip/hip_bf16.h>

// Problem constants (fixed by setup_inputs)
#define T_TOK 4096   // B*S = 4*1024
#define HD    1024   // hidden
#define FD    2048   // ffn
#define NEXP  8
#define NSH   2

using u16 = unsigned short;
typedef __bf16 bf16x8 __attribute__((ext_vector_type(8)));
typedef float  f32x4  __attribute__((ext_vector_type(4)));
typedef u16    u16x2  __attribute__((ext_vector_type(2)));
typedef u16    u16x4  __attribute__((ext_vector_type(4)));

__device__ __forceinline__ u16 f2bf(float f) {
    __hip_bfloat16 h = __float2bfloat16(f);   // RNE
    u16 u; __builtin_memcpy(&u, &h, 2);
    return u;
}
__device__ __forceinline__ float bf2f(u16 u) {
    unsigned v = ((unsigned)u) << 16;
    float f; __builtin_memcpy(&f, &v, 4);
    return f;
}

// async global->LDS, 16B per lane. HW: wave-uniform base + lane*16B.
__device__ __forceinline__ void gl2lds16(const u16* g, u16* l) {
    __builtin_amdgcn_global_load_lds((__attribute__((address_space(1))) void*)(g),
                                     (__attribute__((address_space(3))) void*)(l),
                                     16, 0, 0);
}

// ---------------------------------------------------------------------------
// Core 128x128 tile K-loop (BK=32), 4 waves in 2x2, 4x4 16x16x32 MFMA frags.
// NOTE: the [row][32] u16 layout (64B rows) is already bank-conflict-OPTIMAL
// for the frag ds_read_b128s: bank = 16*(row&1) + quad*4 + e -> 8 accesses
// per bank = the 1KB/instr minimum. Do not swizzle (measured-null regime).
// ---------------------------------------------------------------------------
__device__ __forceinline__ void gemm_k_loop(
    const u16* a0, const u16* a1, const u16* b0, const u16* b1,
    u16* As, u16* Bs, int kIters, f32x4 acc[4][4])
{
    const int tid  = threadIdx.x;
    const int wave = tid >> 6, lane = tid & 63;
    const int wm = wave >> 1, wn = wave & 1;
    const int l16 = lane & 15, quad = lane >> 4;
    u16* lA0 = As + (wave * 32 + 0)  * 32 + lane * 8;
    u16* lA1 = As + (wave * 32 + 16) * 32 + lane * 8;
    u16* lB0 = Bs + (wave * 32 + 0)  * 32 + lane * 8;
    u16* lB1 = Bs + (wave * 32 + 16) * 32 + lane * 8;

    for (int kt = 0; kt < kIters; ++kt) {
        gl2lds16(a0, lA0);
        gl2lds16(a1, lA1);
        gl2lds16(b0, lB0);
        gl2lds16(b1, lB1);
        a0 += 32; a1 += 32; b0 += 32; b1 += 32;
        __syncthreads();
        bf16x8 af[4], bfv[4];
#pragma unroll
        for (int i = 0; i < 4; ++i)
            af[i] = *(const bf16x8*)(As + (wm * 64 + i * 16 + l16) * 32 + quad * 8);
#pragma unroll
        for (int j = 0; j < 4; ++j)
            bfv[j] = *(const bf16x8*)(Bs + (wn * 64 + j * 16 + l16) * 32 + quad * 8);
#pragma unroll
        for (int i = 0; i < 4; ++i)
#pragma unroll
            for (int j = 0; j < 4; ++j)
                acc[i][j] = __builtin_amdgcn_mfma_f32_16x16x32_bf16(af[i], bfv[j], acc[i][j], 0, 0, 0);
        __syncthreads();
    }
}

// tanh-form GELU: max abs err ~1e-3 vs exact erf form — negligible after W2.
__device__ __forceinline__ float gelu_fast(float v) {
    float u = v * (0.7978845608028654f + 0.035677408136300125f * v * v);
    return v * __builtin_amdgcn_rcpf(1.0f + __expf(-2.0f * u));
}

// ---------------------------------------------------------------------------
// Coalesced bf16 epilogue: per-wave private LDS region (16 rows x stride 66
// u16; 4 waves fit in the 16KB staging buffer). STRIDE 66: 33 dwords == 1
// mod 32 -> ds_read_b64 side is 2-way (free) instead of 4-way at stride 68.
// ---------------------------------------------------------------------------
#define EPI_STRIDE 66
template<bool GELU>
__device__ __forceinline__ void epi_store_bf16(
    f32x4 acc[4][4], const float bj[4],
    u16* __restrict__ dst, size_t ld, int rowbase, int colbase, u16* lds)
{
    const int lane = threadIdx.x & 63;
    const int l16 = lane & 15, quad = lane >> 4;
    const int rr = lane >> 2, seg = lane & 3;
#pragma unroll
    for (int i = 0; i < 4; ++i) {
#pragma unroll
        for (int j = 0; j < 4; ++j)
#pragma unroll
            for (int r = 0; r < 4; ++r) {
                float v = acc[i][j][r] + bj[j];
                if (GELU) v = gelu_fast(v);
                lds[(quad * 4 + r) * EPI_STRIDE + j * 16 + l16] = f2bf(v);
            }
        __asm__ volatile("s_waitcnt lgkmcnt(0)" ::: "memory");
        const u16* lp = lds + rr * EPI_STRIDE + seg * 16;
        u16x4 v0 = *(const u16x4*)(lp);
        u16x4 v1 = *(const u16x4*)(lp + 4);
        u16x4 v2 = *(const u16x4*)(lp + 8);
        u16x4 v3 = *(const u16x4*)(lp + 12);
        u16* gp = dst + (size_t)(rowbase + i * 16 + rr) * ld + colbase + seg * 16;
        *(u16x4*)(gp)      = v0;
        *(u16x4*)(gp + 4)  = v1;
        *(u16x4*)(gp + 8)  = v2;
        *(u16x4*)(gp + 12) = v3;
        __asm__ volatile("s_waitcnt lgkmcnt(0)" ::: "memory");  // drain reads before next i overwrites
    }
}

// ---------------------------------------------------------------------------
// T1: 2-D XCD chunk map. Dispatch is x-fastest and round-robins XCDs, so
// xcd = flat&7. Give each XCD a CXxCY sub-rectangle (4 nt-chunks x 2
// mt-chunks): each A-panel is fetched by 4 XCDs (not 8), B chunk stays
// L2-resident. Requires NX*NY % 8 == 0 (holds: 256 / 512). Perf-only.
// ---------------------------------------------------------------------------
template<int NX, int CX, int CY>
__device__ __forceinline__ void xcd_map2d(int& nt, int& mt) {
    const int flat = blockIdx.x + NX * blockIdx.y;
    const int xcd = flat & 7, idx = flat >> 3;
    nt = (xcd & 3) * CX + idx % CX;
    mt = (xcd >> 2) * CY + (idx / CX) % CY;
}

// ---------------------------------------------------------------------------
// Fused convert + router: writes xb (bf16) and fp32 logits top-2 per token.
// ---------------------------------------------------------------------------
__global__ __launch_bounds__(256) void router_convert_kernel(
    const float* __restrict__ x, const float* __restrict__ rw, const float* __restrict__ rb,
    u16* __restrict__ xb, int* __restrict__ cnt, int* __restrict__ lists, int* __restrict__ pos)
{
    const int t = blockIdx.x * 4 + (threadIdx.x >> 6);
    const int lane = threadIdx.x & 63;
    const float* xr = x + (size_t)t * HD;
    u16* xbr = xb + (size_t)t * HD;
    float acc[NEXP];
#pragma unroll
    for (int e = 0; e < NEXP; ++e) acc[e] = 0.f;
#pragma unroll
    for (int it = 0; it < 4; ++it) {
        int h0 = it * 256 + lane * 4;
        float4 v = *(const float4*)(xr + h0);
        ushort4 o = { f2bf(v.x), f2bf(v.y), f2bf(v.z), f2bf(v.w) };
        *(ushort4*)(xbr + h0) = o;
        float xv[4] = { v.x, v.y, v.z, v.w };
#pragma unroll
        for (int q = 0; q < 4; ++q) {
            const float4* wp = (const float4*)(rw + (size_t)(h0 + q) * NEXP);
            float4 w0 = wp[0], w1 = wp[1];
            acc[0] += xv[q] * w0.x; acc[1] += xv[q] * w0.y;
            acc[2] += xv[q] * w0.z; acc[3] += xv[q] * w0.w;
            acc[4] += xv[q] * w1.x; acc[5] += xv[q] * w1.y;
            acc[6] += xv[q] * w1.z; acc[7] += xv[q] * w1.w;
        }
    }
#pragma unroll
    for (int e = 0; e < NEXP; ++e)
        for (int off = 32; off; off >>= 1) acc[e] += __shfl_xor(acc[e], off, 64);
    if (lane == 0) {
#pragma unroll
        for (int e = 0; e < NEXP; ++e) acc[e] += rb[e];
        int b1i = 0;
        for (int e = 1; e < NEXP; ++e) if (acc[e] > acc[b1i]) b1i = e;
        int b2i = (b1i == 0) ? 1 : 0;
        for (int e = 0; e < NEXP; ++e) if (e != b1i && acc[e] > acc[b2i]) b2i = e;
        int p1 = atomicAdd(&cnt[b1i], 1); lists[b1i * T_TOK + p1] = t;
        int p2 = atomicAdd(&cnt[b2i], 1); lists[b2i * T_TOK + p2] = t;
        pos[2 * t]     = (b1i << 13) | p1;
        pos[2 * t + 1] = (b2i << 13) | p2;
    }
}

__global__ void offsets_kernel(const int* __restrict__ cnt, int* __restrict__ pfx) {
    if (threadIdx.x == 0 && blockIdx.x == 0) {
        int s = 0;
        for (int e = 0; e < NEXP; ++e) { pfx[e] = s; s += ((cnt[e] + 127) >> 7) << 7; }
        pfx[NEXP] = s;
    }
}

// ---------------------------------------------------------------------------
// Transposes: fp32 [K,N] -> bf16 [N,K]. 64(dst-contig) x 32 tiles.
// ---------------------------------------------------------------------------
__global__ __launch_bounds__(256) void transpose_w1_kernel(
    const float* __restrict__ sw1, const float* __restrict__ ew1, u16* __restrict__ wt)
{
    __shared__ u16 tile[32][65];
    const int z = blockIdx.z;
    const float* src = (z < NSH) ? (sw1 + (size_t)z * HD * FD)
                                 : (ew1 + (size_t)(z - NSH) * HD * FD);
    u16* dst = wt + (size_t)z * FD * HD;           // [f][h], ld = HD
    const int tx = threadIdx.x, ty = threadIdx.y;  // (32, 8)
    const int c0 = blockIdx.x * 32;                // over FD (dst rows)
    const int r0 = blockIdx.y * 64;                // over HD (dst contig)
#pragma unroll
    for (int k = 0; k < 8; ++k)
        tile[tx][ty + 8 * k] = f2bf(src[(size_t)(r0 + ty + 8 * k) * FD + c0 + tx]);
    __syncthreads();
#pragma unroll
    for (int k = 0; k < 4; ++k) {
        int c = ty + 8 * k;
        u16x2 v = { tile[c][2 * tx], tile[c][2 * tx + 1] };
        *(u16x2*)(dst + (size_t)(c0 + c) * HD + r0 + 2 * tx) = v;
    }
}

// shared_w2[s][f][h] -> w2tS[h][s*FD+f] (ld=2FD);  exp_w2[e][f][h] -> [e][h][f]
__global__ __launch_bounds__(256) void transpose_w2_kernel(
    const float* __restrict__ sw2, const float* __restrict__ ew2, u16* __restrict__ wt)
{
    __shared__ u16 tile[32][65];
    const int z = blockIdx.z;
    const float* src; u16* dst; size_t ldd;
    if (z < NSH) { src = sw2 + (size_t)z * FD * HD; dst = wt + (size_t)z * FD; ldd = 2 * FD; }
    else { src = ew2 + (size_t)(z - NSH) * FD * HD;
           dst = wt + (size_t)NSH * FD * HD + (size_t)(z - NSH) * HD * FD; ldd = FD; }
    const int tx = threadIdx.x, ty = threadIdx.y;  // (32, 8)
    const int c0 = blockIdx.x * 32;                // over HD (dst rows h)
    const int r0 = blockIdx.y * 64;                // over FD (dst contig f)
#pragma unroll
    for (int k = 0; k < 8; ++k)
        tile[tx][ty + 8 * k] = f2bf(src[(size_t)(r0 + ty + 8 * k) * HD + c0 + tx]);
    __syncthreads();
#pragma unroll
    for (int k = 0; k < 4; ++k) {
        int c = ty + 8 * k;
        u16x2 v = { tile[c][2 * tx], tile[c][2 * tx + 1] };
        *(u16x2*)(dst + (size_t)(c0 + c) * ldd + r0 + 2 * tx) = v;
    }
}

// ---------------------------------------------------------------------------
// GEMM1 merged: z<NSH -> shared expert s=z (hidS[t][s*FD+f]);
//               z>=NSH -> routed expert e=z-NSH (hidE[pfx[e]+slot][f]).
// Shared planes use the 2-D XCD chunk map (A-panel fetched by 4 XCDs not 8).
// ---------------------------------------------------------------------------
__global__ __launch_bounds__(256, 4) void gemm1_all_kernel(
    const u16* __restrict__ xb, const u16* __restrict__ w1t,
    const float* __restrict__ sb1, const float* __restrict__ eb1,
    const int* __restrict__ cnt, const int* __restrict__ pfx,
    const int* __restrict__ lists,
    u16* __restrict__ hidS, u16* __restrict__ hidE)
{
    const int z = blockIdx.z;
    const bool routed = (z >= NSH);
    const int e = z - NSH;
    int nt, mt;
    if (!routed) xcd_map2d<FD / 128, 4, 16>(nt, mt);          // 16x32 grid -> 4x16 chunks
    else { nt = blockIdx.x; mt = blockIdx.y; }                // B-stationary (xcd = nt%8)
    if (routed && mt * 128 >= cnt[e]) return;   // block-uniform early exit
    __shared__ __align__(16) u16 S[2 * 128 * 32];
    u16* As = S;
    u16* Bs = S + 128 * 32;
    const int tid = threadIdx.x, wave = tid >> 6, lane = tid & 63;
    const int r0 = wave * 32 + (lane >> 2), ch = (lane & 3) * 8;
    const u16 *a0, *a1;
    if (routed) {
        int tok0 = lists[e * T_TOK + mt * 128 + r0];
        int tok1 = lists[e * T_TOK + mt * 128 + r0 + 16];
        a0 = xb + (size_t)tok0 * HD + ch;
        a1 = xb + (size_t)tok1 * HD + ch;
    } else {
        a0 = xb + (size_t)(mt * 128 + r0) * HD + ch;
        a1 = a0 + (size_t)16 * HD;
    }
    const u16* b0 = w1t + (size_t)z * FD * HD + (size_t)(nt * 128 + r0) * HD + ch;
    const u16* b1 = b0 + (size_t)16 * HD;
    f32x4 acc[4][4] = {};
    gemm_k_loop(a0, a1, b0, b1, As, Bs, HD / 32, acc);

    const int wm = wave >> 1, wn = wave & 1, l16 = lane & 15;
    const float* bias = routed ? (eb1 + e * FD) : (sb1 + z * FD);
    float bj[4];
#pragma unroll
    for (int j = 0; j < 4; ++j) bj[j] = bias[nt * 128 + wn * 64 + j * 16 + l16];
    u16* dst   = routed ? hidE : hidS;
    const size_t ld = routed ? FD : 2 * FD;
    const int rowbase = (routed ? (pfx[e] + mt * 128) : (mt * 128)) + wm * 64;
    const int colbase = (routed ? 0 : z * FD) + nt * 128 + wn * 64;
    epi_store_bf16<true>(acc, bj, dst, ld, rowbase, colbase, S + wave * 16 * EPI_STRIDE);
}

// ---------------------------------------------------------------------------
// GEMM2 merged, NO atomics: z==0 -> shared (K=4096 over both experts, plain
// fp32 stores directly to out w/ both biases); z>=1 -> routed expert e=z-1
// (K=2048, coalesced bf16 stores to routedOut[slot] w/ bias).
// z==0 uses the 2-D XCD chunk map (this was the 268 MB A-refetch source).
// ---------------------------------------------------------------------------
__global__ __launch_bounds__(256, 4) void gemm2_all_kernel(
    const u16* __restrict__ hidS, const u16* __restrict__ hidE,
    const u16* __restrict__ w2t,
    const float* __restrict__ sb2, const float* __restrict__ eb2,
    const int* __restrict__ cnt, const int* __restrict__ pfx,
    float* __restrict__ out, u16* __restrict__ routedOut)
{
    const int z = blockIdx.z;
    const int e = z - 1;
    int nt, mt;
    if (z == 0) xcd_map2d<HD / 128, 2, 16>(nt, mt);           // 8x32 grid -> 2x16 chunks
    else { nt = blockIdx.x; mt = blockIdx.y; }
    if (z >= 1 && mt * 128 >= cnt[e]) return;
    __shared__ __align__(16) u16 S[2 * 128 * 32];
    u16* As = S;
    u16* Bs = S + 128 * 32;
    const int tid = threadIdx.x, wave = tid >> 6, lane = tid & 63;
    const int r0 = wave * 32 + (lane >> 2), ch = (lane & 3) * 8;
    const int wm = wave >> 1, wn = wave & 1, l16 = lane & 15, quad = lane >> 4;
    f32x4 acc[4][4] = {};

    if (z == 0) {
        const u16* a0 = hidS + (size_t)(mt * 128 + r0) * (2 * FD) + ch;
        const u16* a1 = a0 + (size_t)16 * (2 * FD);
        const u16* b0 = w2t + (size_t)(nt * 128 + r0) * (2 * FD) + ch;
        const u16* b1 = b0 + (size_t)16 * (2 * FD);
        gemm_k_loop(a0, a1, b0, b1, As, Bs, (2 * FD) / 32, acc);
#pragma unroll
        for (int j = 0; j < 4; ++j) {
            int h = nt * 128 + wn * 64 + j * 16 + l16;
            float bv = sb2[h] + sb2[HD + h];
#pragma unroll
            for (int i = 0; i < 4; ++i) {
                int row = mt * 128 + wm * 64 + i * 16 + quad * 4;
#pragma unroll
                for (int r = 0; r < 4; ++r)
                    out[(size_t)(row + r) * HD + h] = acc[i][j][r] + bv;
            }
        }
    } else {
        const int base = pfx[e];
        const u16* a0 = hidE + (size_t)(base + mt * 128 + r0) * FD + ch;
        const u16* a1 = a0 + (size_t)16 * FD;
        const u16* b0 = w2t + (size_t)NSH * FD * HD + (size_t)e * HD * FD
                            + (size_t)(nt * 128 + r0) * FD + ch;
        const u16* b1 = b0 + (size_t)16 * FD;
        gemm_k_loop(a0, a1, b0, b1, As, Bs, FD / 32, acc);
        float bj[4];
#pragma unroll
        for (int j = 0; j < 4; ++j) bj[j] = eb2[e * HD + nt * 128 + wn * 64 + j * 16 + l16];
        epi_store_bf16<false>(acc, bj, routedOut, HD,
                              base + mt * 128 + wm * 64, nt * 128 + wn * 64,
                              S + wave * 16 * EPI_STRIDE);
    }
}

// Fallback (small-ws): routed scatters via atomicAdd onto out (which the
// shared pass already fully wrote). K unsplit, bias added once per (t,h,e).
__global__ __launch_bounds__(256, 4) void gemm2_routed_atomic_kernel(
    const u16* __restrict__ hidE, const u16* __restrict__ w2t,
    const float* __restrict__ eb2, const int* __restrict__ cnt,
    const int* __restrict__ pfx, const int* __restrict__ lists,
    float* __restrict__ out)
{
    const int e = blockIdx.z, nt = blockIdx.x, mt = blockIdx.y;
    const int n_e = cnt[e];
    if (mt * 128 >= n_e) return;
    __shared__ __align__(16) u16 S[2 * 128 * 32];
    u16* As = S;
    u16* Bs = S + 128 * 32;
    const int tid = threadIdx.x, wave = tid >> 6, lane = tid & 63;
    const int r0 = wave * 32 + (lane >> 2), ch = (lane & 3) * 8;
    const int base = pfx[e];
    const u16* a0 = hidE + (size_t)(base + mt * 128 + r0) * FD + ch;
    const u16* a1 = a0 + (size_t)16 * FD;
    const u16* b0 = w2t + (size_t)NSH * FD * HD + (size_t)e * HD * FD
                        + (size_t)(nt * 128 + r0) * FD + ch;
    const u16* b1 = b0 + (size_t)16 * FD;
    f32x4 acc[4][4] = {};
    gemm_k_loop(a0, a1, b0, b1, As, Bs, FD / 32, acc);
    const int wm = wave >> 1, wn = wave & 1, l16 = lane & 15, quad = lane >> 4;
#pragma unroll
    for (int j = 0; j < 4; ++j) {
        int h = nt * 128 + wn * 64 + j * 16 + l16;
        float bv = eb2[e * HD + h];
#pragma unroll
        for (int i = 0; i < 4; ++i) {
            int local = mt * 128 + wm * 64 + i * 16 + quad * 4;
#pragma unroll
            for (int r = 0; r < 4; ++r)
                if (local + r < n_e) {
                    int t = lists[e * T_TOK + local + r];
                    atomicAdd(&out[(size_t)t * HD + h], acc[i][j][r] + bv);
                }
        }
    }
}

// out[t][:] += routedOut[row1][:] + routedOut[row2][:]
__global__ __launch_bounds__(256) void finalize_kernel(
    const u16* __restrict__ routedOut, const int* __restrict__ pos,
    const int* __restrict__ pfx, float* __restrict__ out)
{
    const int t = blockIdx.x;
    int enc0 = pos[2 * t], enc1 = pos[2 * t + 1];
    int row0 = pfx[enc0 >> 13] + (enc0 & 8191);
    int row1 = pfx[enc1 >> 13] + (enc1 & 8191);
    int h = threadIdx.x * 4;
    ushort4 a = *(const ushort4*)(routedOut + (size_t)row0 * HD + h);
    ushort4 b = *(const ushort4*)(routedOut + (size_t)row1 * HD + h);
    float* po = out + (size_t)t * HD + h;
    float4 o = *(const float4*)po;
    o.x += bf2f(a.x) + bf2f(b.x);
    o.y += bf2f(a.y) + bf2f(b.y);
    o.z += bf2f(a.z) + bf2f(b.z);
    o.w += bf2f(a.w) + bf2f(b.w);
    *(float4*)po = o;
}

// ---------------------------------------------------------------------------
// Workspace layout (bytes):
//   wt        @ 0           : 41,943,040  (w1^T, later reused for w2^T)
//   hidS      @ 41,943,040  : 33,554,432  (bf16 [4096][2*FD])
//   hidE      @ 75,497,472  : 37,748,736  (bf16 [9216][FD])
//   xb        @ 113,246,208 :  8,388,608  (dead after gemm1)
//   routedOut @ 113,246,208 : 18,874,368  (overlays xb; lifetimes disjoint)
// primary: smalls @ 132,120,576 (cnt 64 | pfx 64 | lists 131072 | pos 32768)
//          -> total 132,284,544
// fallback: smalls @ 121,634,816 -> total 121,798,784 (proven-safe size)
// ---------------------------------------------------------------------------
extern "C" void kernel_launch(void* const* d_in, const int* in_sizes, int n_in,
                              void* d_out, int out_size, void* d_ws, size_t ws_size,
                              hipStream_t stream)
{
    (void)in_sizes; (void)n_in; (void)out_size;
    const float* x   = (const float*)d_in[0];
    const float* sw1 = (const float*)d_in[1];
    const float* sb1 = (const float*)d_in[2];
    const float* sw2 = (const float*)d_in[3];
    const float* sb2 = (const float*)d_in[4];
    const float* ew1 = (const float*)d_in[5];
    const float* eb1 = (const float*)d_in[6];
    const float* ew2 = (const float*)d_in[7];
    const float* eb2 = (const float*)d_in[8];
    const float* rw  = (const float*)d_in[9];
    const float* rb  = (const float*)d_in[10];
    float* out = (float*)d_out;

    const bool plain = (ws_size >= (size_t)132284544);
    char* ws   = (char*)d_ws;
    u16*  wt   = (u16*)ws;
    u16*  hidS = (u16*)(ws + 41943040);
    u16*  hidE = (u16*)(ws + 75497472);
    u16*  xb   = (u16*)(ws + 113246208);
    u16*  rOut = (u16*)(ws + 113246208);   // overlays xb
    size_t smallOfs = plain ? (size_t)132120576 : (size_t)121634816;
    int*  cnt   = (int*)(ws + smallOfs);
    int*  pfx   = (int*)(ws + smallOfs + 64);
    int*  lists = (int*)(ws + smallOfs + 128);
    int*  pos   = (int*)(ws + smallOfs + 128 + NEXP * T_TOK * 4);

    hipMemsetAsync(cnt, 0, 128 + (size_t)NEXP * T_TOK * 4, stream);  // cnt+pfx+lists

    router_convert_kernel<<<dim3(T_TOK / 4), dim3(256), 0, stream>>>(x, rw, rb, xb, cnt, lists, pos);
    offsets_kernel<<<dim3(1), dim3(64), 0, stream>>>(cnt, pfx);
    transpose_w1_kernel<<<dim3(FD / 32, HD / 64, NSH + NEXP), dim3(32, 8), 0, stream>>>(sw1, ew1, wt);

    gemm1_all_kernel<<<dim3(FD / 128, T_TOK / 128, NSH + NEXP), dim3(256), 0, stream>>>(
        xb, wt, sb1, eb1, cnt, pfx, lists, hidS, hidE);

    transpose_w2_kernel<<<dim3(HD / 32, FD / 64, NSH + NEXP), dim3(32, 8), 0, stream>>>(sw2, ew2, wt);

    if (plain) {
        gemm2_all_kernel<<<dim3(HD / 128, T_TOK / 128, 1 + NEXP), dim3(256), 0, stream>>>(
            hidS, hidE, wt, sb2, eb2, cnt, pfx, out, rOut);
        finalize_kernel<<<dim3(T_TOK), dim3(256), 0, stream>>>(rOut, pos, pfx, out);
    } else {
        gemm2_all_kernel<<<dim3(HD / 128, T_TOK / 128, 1), dim3(256), 0, stream>>>(
            hidS, hidE, wt, sb2, eb2, cnt, pfx, out, rOut);  // z=0 shared only
        gemm2_routed_atomic_kernel<<<dim3(HD / 128, T_TOK / 128, NEXP), dim3(256), 0, stream>>>(
            hidE, wt, eb2, cnt, pfx, lists, out);
    }
}

// Round 3
// 527.167 us; speedup vs baseline: 1.1139x; 1.0063x over previous
//
#include <hip/hip_runtime.h>
#include <hip/hip_bf16.h>

// Problem constants (fixed by setup_inputs)
#define T_TOK 4096   // B*S = 4*1024
#define HD    1024   // hidden
#define FD    2048   // ffn
#define NEXP  8
#define NSH   2

using u16 = unsigned short;
typedef __bf16 bf16x8 __attribute__((ext_vector_type(8)));
typedef float  f32x4  __attribute__((ext_vector_type(4)));
typedef u16    u16x2  __attribute__((ext_vector_type(2)));
typedef u16    u16x4  __attribute__((ext_vector_type(4)));

__device__ __forceinline__ u16 f2bf(float f) {
    __hip_bfloat16 h = __float2bfloat16(f);   // RNE
    u16 u; __builtin_memcpy(&u, &h, 2);
    return u;
}
__device__ __forceinline__ float bf2f(u16 u) {
    unsigned v = ((unsigned)u) << 16;
    float f; __builtin_memcpy(&f, &v, 4);
    return f;
}

// async global->LDS, 16B per lane. HW: wave-uniform base + lane*16B.
__device__ __forceinline__ void gl2lds16(const u16* g, u16* l) {
    __builtin_amdgcn_global_load_lds((__attribute__((address_space(1))) void*)(g),
                                     (__attribute__((address_space(3))) void*)(l),
                                     16, 0, 0);
}

// ---------------------------------------------------------------------------
// Core 128x128 tile K-loop (BK=32), 4 waves in 2x2, 4x4 16x16x32 MFMA frags.
// T3-minimum schedule: double-buffered LDS (A/B x 2 bufs = 32 KB); next
// tile's global_load_lds issued BEFORE current tile's ds_read+MFMA; ONE
// __syncthreads per K-step (its vmcnt(0) drains the prefetch ~300cy after
// issue, mostly covered by reads+MFMA).
// Bank swizzle (both-sides, rule #21): physical 16B-chunk = logical ^
// ((row>>1)&3). Write side via pre-swizzled GLOBAL source (callers: ch =
// ((lane&3)^((lane>>3)&3))*8 — same term for both staged rows r, r+16);
// read side XOR on the ds_read address. Each 8-lane issue group then hits
// all 32 banks exactly once (was 8 banks x 4-way = the 8.9M conflicts).
// ---------------------------------------------------------------------------
__device__ __forceinline__ void gemm_k_loop(
    const u16* a0, const u16* a1, const u16* b0, const u16* b1,
    u16* S, int kIters, f32x4 acc[4][4])
{
    const int tid  = threadIdx.x;
    const int wave = tid >> 6, lane = tid & 63;
    const int wm = wave >> 1, wn = wave & 1;
    const int l16 = lane & 15, quad = lane >> 4;
    const int xs = (l16 >> 1) & 3;             // read-side chunk swizzle
    const int dA0 = (wave * 32 + 0)  * 32 + lane * 8;
    const int dA1 = (wave * 32 + 16) * 32 + lane * 8;
    // buffers: A @ buf*8192, B @ buf*8192 + 4096 (u16 units)
    gl2lds16(a0, S + dA0);
    gl2lds16(a1, S + dA1);
    gl2lds16(b0, S + 4096 + dA0);
    gl2lds16(b1, S + 4096 + dA1);
    a0 += 32; a1 += 32; b0 += 32; b1 += 32;
    __syncthreads();
    for (int kt = 0; kt < kIters; ++kt) {
        const int cur = kt & 1;
        u16* Sn = S + (cur ^ 1) * 8192;
        if (kt + 1 < kIters) {                 // prefetch next tile (uniform)
            gl2lds16(a0, Sn + dA0);
            gl2lds16(a1, Sn + dA1);
            gl2lds16(b0, Sn + 4096 + dA0);
            gl2lds16(b1, Sn + 4096 + dA1);
            a0 += 32; a1 += 32; b0 += 32; b1 += 32;
        }
        const u16* As = S + cur * 8192;
        const u16* Bs = As + 4096;
        bf16x8 af[4], bfv[4];
#pragma unroll
        for (int i = 0; i < 4; ++i)
            af[i] = *(const bf16x8*)(As + (wm * 64 + i * 16 + l16) * 32 + ((quad ^ xs) * 8));
#pragma unroll
        for (int j = 0; j < 4; ++j)
            bfv[j] = *(const bf16x8*)(Bs + (wn * 64 + j * 16 + l16) * 32 + ((quad ^ xs) * 8));
#pragma unroll
        for (int i = 0; i < 4; ++i)
#pragma unroll
            for (int j = 0; j < 4; ++j)
                acc[i][j] = __builtin_amdgcn_mfma_f32_16x16x32_bf16(af[i], bfv[j], acc[i][j], 0, 0, 0);
        __syncthreads();   // vmcnt(0)+lgkmcnt(0)+barrier: prefetch landed, reads done
    }
}

// tanh-form GELU: max abs err ~1e-3 vs exact erf form — negligible after W2.
__device__ __forceinline__ float gelu_fast(float v) {
    float u = v * (0.7978845608028654f + 0.035677408136300125f * v * v);
    return v * __builtin_amdgcn_rcpf(1.0f + __expf(-2.0f * u));
}

// ---------------------------------------------------------------------------
// Coalesced bf16 epilogue: per-wave private LDS region (16 rows x stride 66
// u16; 4 waves fit in the staging buffer after the K-loop's final barrier).
// ---------------------------------------------------------------------------
#define EPI_STRIDE 66
template<bool GELU>
__device__ __forceinline__ void epi_store_bf16(
    f32x4 acc[4][4], const float bj[4],
    u16* __restrict__ dst, size_t ld, int rowbase, int colbase, u16* lds)
{
    const int lane = threadIdx.x & 63;
    const int l16 = lane & 15, quad = lane >> 4;
    const int rr = lane >> 2, seg = lane & 3;
#pragma unroll
    for (int i = 0; i < 4; ++i) {
#pragma unroll
        for (int j = 0; j < 4; ++j)
#pragma unroll
            for (int r = 0; r < 4; ++r) {
                float v = acc[i][j][r] + bj[j];
                if (GELU) v = gelu_fast(v);
                lds[(quad * 4 + r) * EPI_STRIDE + j * 16 + l16] = f2bf(v);
            }
        __asm__ volatile("s_waitcnt lgkmcnt(0)" ::: "memory");
        const u16* lp = lds + rr * EPI_STRIDE + seg * 16;
        u16x4 v0 = *(const u16x4*)(lp);
        u16x4 v1 = *(const u16x4*)(lp + 4);
        u16x4 v2 = *(const u16x4*)(lp + 8);
        u16x4 v3 = *(const u16x4*)(lp + 12);
        u16* gp = dst + (size_t)(rowbase + i * 16 + rr) * ld + colbase + seg * 16;
        *(u16x4*)(gp)      = v0;
        *(u16x4*)(gp + 4)  = v1;
        *(u16x4*)(gp + 8)  = v2;
        *(u16x4*)(gp + 12) = v3;
        __asm__ volatile("s_waitcnt lgkmcnt(0)" ::: "memory");  // drain reads before next i overwrites
    }
}

// ---------------------------------------------------------------------------
// T1: 2-D XCD chunk map. Dispatch is x-fastest and round-robins XCDs, so
// xcd = flat&7. Give each XCD a CXxCY sub-rectangle: A-panel fetched by 4
// XCDs (not 8), B chunk stays L2-resident. (Round-2: FETCH 322->272 MB.)
// ---------------------------------------------------------------------------
template<int NX, int CX, int CY>
__device__ __forceinline__ void xcd_map2d(int& nt, int& mt) {
    const int flat = blockIdx.x + NX * blockIdx.y;
    const int xcd = flat & 7, idx = flat >> 3;
    nt = (xcd & 3) * CX + idx % CX;
    mt = (xcd >> 2) * CY + (idx / CX) % CY;
}

// ---------------------------------------------------------------------------
// Fused convert + router: writes xb (bf16) and fp32 logits top-2 per token.
// ---------------------------------------------------------------------------
__global__ __launch_bounds__(256) void router_convert_kernel(
    const float* __restrict__ x, const float* __restrict__ rw, const float* __restrict__ rb,
    u16* __restrict__ xb, int* __restrict__ cnt, int* __restrict__ lists, int* __restrict__ pos)
{
    const int t = blockIdx.x * 4 + (threadIdx.x >> 6);
    const int lane = threadIdx.x & 63;
    const float* xr = x + (size_t)t * HD;
    u16* xbr = xb + (size_t)t * HD;
    float acc[NEXP];
#pragma unroll
    for (int e = 0; e < NEXP; ++e) acc[e] = 0.f;
#pragma unroll
    for (int it = 0; it < 4; ++it) {
        int h0 = it * 256 + lane * 4;
        float4 v = *(const float4*)(xr + h0);
        ushort4 o = { f2bf(v.x), f2bf(v.y), f2bf(v.z), f2bf(v.w) };
        *(ushort4*)(xbr + h0) = o;
        float xv[4] = { v.x, v.y, v.z, v.w };
#pragma unroll
        for (int q = 0; q < 4; ++q) {
            const float4* wp = (const float4*)(rw + (size_t)(h0 + q) * NEXP);
            float4 w0 = wp[0], w1 = wp[1];
            acc[0] += xv[q] * w0.x; acc[1] += xv[q] * w0.y;
            acc[2] += xv[q] * w0.z; acc[3] += xv[q] * w0.w;
            acc[4] += xv[q] * w1.x; acc[5] += xv[q] * w1.y;
            acc[6] += xv[q] * w1.z; acc[7] += xv[q] * w1.w;
        }
    }
#pragma unroll
    for (int e = 0; e < NEXP; ++e)
        for (int off = 32; off; off >>= 1) acc[e] += __shfl_xor(acc[e], off, 64);
    if (lane == 0) {
#pragma unroll
        for (int e = 0; e < NEXP; ++e) acc[e] += rb[e];
        int b1i = 0;
        for (int e = 1; e < NEXP; ++e) if (acc[e] > acc[b1i]) b1i = e;
        int b2i = (b1i == 0) ? 1 : 0;
        for (int e = 0; e < NEXP; ++e) if (e != b1i && acc[e] > acc[b2i]) b2i = e;
        int p1 = atomicAdd(&cnt[b1i], 1); lists[b1i * T_TOK + p1] = t;
        int p2 = atomicAdd(&cnt[b2i], 1); lists[b2i * T_TOK + p2] = t;
        pos[2 * t]     = (b1i << 13) | p1;
        pos[2 * t + 1] = (b2i << 13) | p2;
    }
}

__global__ void offsets_kernel(const int* __restrict__ cnt, int* __restrict__ pfx) {
    if (threadIdx.x == 0 && blockIdx.x == 0) {
        int s = 0;
        for (int e = 0; e < NEXP; ++e) { pfx[e] = s; s += ((cnt[e] + 127) >> 7) << 7; }
        pfx[NEXP] = s;
    }
}

// ---------------------------------------------------------------------------
// Transposes: fp32 [K,N] -> bf16 [N,K]. 64(dst-contig) x 32 tiles.
// ---------------------------------------------------------------------------
__global__ __launch_bounds__(256) void transpose_w1_kernel(
    const float* __restrict__ sw1, const float* __restrict__ ew1, u16* __restrict__ wt)
{
    __shared__ u16 tile[32][65];
    const int z = blockIdx.z;
    const float* src = (z < NSH) ? (sw1 + (size_t)z * HD * FD)
                                 : (ew1 + (size_t)(z - NSH) * HD * FD);
    u16* dst = wt + (size_t)z * FD * HD;           // [f][h], ld = HD
    const int tx = threadIdx.x, ty = threadIdx.y;  // (32, 8)
    const int c0 = blockIdx.x * 32;                // over FD (dst rows)
    const int r0 = blockIdx.y * 64;                // over HD (dst contig)
#pragma unroll
    for (int k = 0; k < 8; ++k)
        tile[tx][ty + 8 * k] = f2bf(src[(size_t)(r0 + ty + 8 * k) * FD + c0 + tx]);
    __syncthreads();
#pragma unroll
    for (int k = 0; k < 4; ++k) {
        int c = ty + 8 * k;
        u16x2 v = { tile[c][2 * tx], tile[c][2 * tx + 1] };
        *(u16x2*)(dst + (size_t)(c0 + c) * HD + r0 + 2 * tx) = v;
    }
}

// shared_w2[s][f][h] -> w2tS[h][s*FD+f] (ld=2FD);  exp_w2[e][f][h] -> [e][h][f]
__global__ __launch_bounds__(256) void transpose_w2_kernel(
    const float* __restrict__ sw2, const float* __restrict__ ew2, u16* __restrict__ wt)
{
    __shared__ u16 tile[32][65];
    const int z = blockIdx.z;
    const float* src; u16* dst; size_t ldd;
    if (z < NSH) { src = sw2 + (size_t)z * FD * HD; dst = wt + (size_t)z * FD; ldd = 2 * FD; }
    else { src = ew2 + (size_t)(z - NSH) * FD * HD;
           dst = wt + (size_t)NSH * FD * HD + (size_t)(z - NSH) * HD * FD; ldd = FD; }
    const int tx = threadIdx.x, ty = threadIdx.y;  // (32, 8)
    const int c0 = blockIdx.x * 32;                // over HD (dst rows h)
    const int r0 = blockIdx.y * 64;                // over FD (dst contig f)
#pragma unroll
    for (int k = 0; k < 8; ++k)
        tile[tx][ty + 8 * k] = f2bf(src[(size_t)(r0 + ty + 8 * k) * HD + c0 + tx]);
    __syncthreads();
#pragma unroll
    for (int k = 0; k < 4; ++k) {
        int c = ty + 8 * k;
        u16x2 v = { tile[c][2 * tx], tile[c][2 * tx + 1] };
        *(u16x2*)(dst + (size_t)(c0 + c) * ldd + r0 + 2 * tx) = v;
    }
}

// ---------------------------------------------------------------------------
// GEMM1 merged: z<NSH -> shared expert s=z (hidS[t][s*FD+f]);
//               z>=NSH -> routed expert e=z-NSH (hidE[pfx[e]+slot][f]).
// ---------------------------------------------------------------------------
__global__ __launch_bounds__(256, 4) void gemm1_all_kernel(
    const u16* __restrict__ xb, const u16* __restrict__ w1t,
    const float* __restrict__ sb1, const float* __restrict__ eb1,
    const int* __restrict__ cnt, const int* __restrict__ pfx,
    const int* __restrict__ lists,
    u16* __restrict__ hidS, u16* __restrict__ hidE)
{
    const int z = blockIdx.z;
    const bool routed = (z >= NSH);
    const int e = z - NSH;
    int nt, mt;
    if (!routed) xcd_map2d<FD / 128, 4, 16>(nt, mt);          // 16x32 grid -> 4x16 chunks
    else { nt = blockIdx.x; mt = blockIdx.y; }                // B-stationary (xcd = nt%8)
    if (routed && mt * 128 >= cnt[e]) return;   // block-uniform early exit
    __shared__ __align__(16) u16 S[4 * 4096];   // 32 KB double-buffered
    const int tid = threadIdx.x, wave = tid >> 6, lane = tid & 63;
    const int r0 = wave * 32 + (lane >> 2);
    const int ch = ((lane & 3) ^ ((lane >> 3) & 3)) * 8;   // pre-swizzled source chunk
    const u16 *a0, *a1;
    if (routed) {
        int tok0 = lists[e * T_TOK + mt * 128 + r0];
        int tok1 = lists[e * T_TOK + mt * 128 + r0 + 16];
        a0 = xb + (size_t)tok0 * HD + ch;
        a1 = xb + (size_t)tok1 * HD + ch;
    } else {
        a0 = xb + (size_t)(mt * 128 + r0) * HD + ch;
        a1 = a0 + (size_t)16 * HD;
    }
    const u16* b0 = w1t + (size_t)z * FD * HD + (size_t)(nt * 128 + r0) * HD + ch;
    const u16* b1 = b0 + (size_t)16 * HD;
    f32x4 acc[4][4] = {};
    gemm_k_loop(a0, a1, b0, b1, S, HD / 32, acc);

    const int wm = wave >> 1, wn = wave & 1, l16 = lane & 15;
    const float* bias = routed ? (eb1 + e * FD) : (sb1 + z * FD);
    float bj[4];
#pragma unroll
    for (int j = 0; j < 4; ++j) bj[j] = bias[nt * 128 + wn * 64 + j * 16 + l16];
    u16* dst   = routed ? hidE : hidS;
    const size_t ld = routed ? FD : 2 * FD;
    const int rowbase = (routed ? (pfx[e] + mt * 128) : (mt * 128)) + wm * 64;
    const int colbase = (routed ? 0 : z * FD) + nt * 128 + wn * 64;
    epi_store_bf16<true>(acc, bj, dst, ld, rowbase, colbase, S + wave * 16 * EPI_STRIDE);
}

// ---------------------------------------------------------------------------
// GEMM2 merged, NO atomics: z==0 -> shared (K=4096 over both experts, plain
// fp32 stores directly to out w/ both biases); z>=1 -> routed expert e=z-1
// (K=2048, coalesced bf16 stores to routedOut[slot] w/ bias).
// ---------------------------------------------------------------------------
__global__ __launch_bounds__(256, 4) void gemm2_all_kernel(
    const u16* __restrict__ hidS, const u16* __restrict__ hidE,
    const u16* __restrict__ w2t,
    const float* __restrict__ sb2, const float* __restrict__ eb2,
    const int* __restrict__ cnt, const int* __restrict__ pfx,
    float* __restrict__ out, u16* __restrict__ routedOut)
{
    const int z = blockIdx.z;
    const int e = z - 1;
    int nt, mt;
    if (z == 0) xcd_map2d<HD / 128, 2, 16>(nt, mt);           // 8x32 grid -> 2x16 chunks
    else { nt = blockIdx.x; mt = blockIdx.y; }
    if (z >= 1 && mt * 128 >= cnt[e]) return;
    __shared__ __align__(16) u16 S[4 * 4096];
    const int tid = threadIdx.x, wave = tid >> 6, lane = tid & 63;
    const int r0 = wave * 32 + (lane >> 2);
    const int ch = ((lane & 3) ^ ((lane >> 3) & 3)) * 8;
    const int wm = wave >> 1, wn = wave & 1, l16 = lane & 15, quad = lane >> 4;
    f32x4 acc[4][4] = {};

    if (z == 0) {
        const u16* a0 = hidS + (size_t)(mt * 128 + r0) * (2 * FD) + ch;
        const u16* a1 = a0 + (size_t)16 * (2 * FD);
        const u16* b0 = w2t + (size_t)(nt * 128 + r0) * (2 * FD) + ch;
        const u16* b1 = b0 + (size_t)16 * (2 * FD);
        gemm_k_loop(a0, a1, b0, b1, S, (2 * FD) / 32, acc);
#pragma unroll
        for (int j = 0; j < 4; ++j) {
            int h = nt * 128 + wn * 64 + j * 16 + l16;
            float bv = sb2[h] + sb2[HD + h];
#pragma unroll
            for (int i = 0; i < 4; ++i) {
                int row = mt * 128 + wm * 64 + i * 16 + quad * 4;
#pragma unroll
                for (int r = 0; r < 4; ++r)
                    out[(size_t)(row + r) * HD + h] = acc[i][j][r] + bv;
            }
        }
    } else {
        const int base = pfx[e];
        const u16* a0 = hidE + (size_t)(base + mt * 128 + r0) * FD + ch;
        const u16* a1 = a0 + (size_t)16 * FD;
        const u16* b0 = w2t + (size_t)NSH * FD * HD + (size_t)e * HD * FD
                            + (size_t)(nt * 128 + r0) * FD + ch;
        const u16* b1 = b0 + (size_t)16 * FD;
        gemm_k_loop(a0, a1, b0, b1, S, FD / 32, acc);
        float bj[4];
#pragma unroll
        for (int j = 0; j < 4; ++j) bj[j] = eb2[e * HD + nt * 128 + wn * 64 + j * 16 + l16];
        epi_store_bf16<false>(acc, bj, routedOut, HD,
                              base + mt * 128 + wm * 64, nt * 128 + wn * 64,
                              S + wave * 16 * EPI_STRIDE);
    }
}

// Fallback (small-ws): routed scatters via atomicAdd onto out (which the
// shared pass already fully wrote). K unsplit, bias added once per (t,h,e).
__global__ __launch_bounds__(256, 4) void gemm2_routed_atomic_kernel(
    const u16* __restrict__ hidE, const u16* __restrict__ w2t,
    const float* __restrict__ eb2, const int* __restrict__ cnt,
    const int* __restrict__ pfx, const int* __restrict__ lists,
    float* __restrict__ out)
{
    const int e = blockIdx.z, nt = blockIdx.x, mt = blockIdx.y;
    const int n_e = cnt[e];
    if (mt * 128 >= n_e) return;
    __shared__ __align__(16) u16 S[4 * 4096];
    const int tid = threadIdx.x, wave = tid >> 6, lane = tid & 63;
    const int r0 = wave * 32 + (lane >> 2);
    const int ch = ((lane & 3) ^ ((lane >> 3) & 3)) * 8;
    const int base = pfx[e];
    const u16* a0 = hidE + (size_t)(base + mt * 128 + r0) * FD + ch;
    const u16* a1 = a0 + (size_t)16 * FD;
    const u16* b0 = w2t + (size_t)NSH * FD * HD + (size_t)e * HD * FD
                        + (size_t)(nt * 128 + r0) * FD + ch;
    const u16* b1 = b0 + (size_t)16 * FD;
    f32x4 acc[4][4] = {};
    gemm_k_loop(a0, a1, b0, b1, S, FD / 32, acc);
    const int wm = wave >> 1, wn = wave & 1, l16 = lane & 15, quad = lane >> 4;
#pragma unroll
    for (int j = 0; j < 4; ++j) {
        int h = nt * 128 + wn * 64 + j * 16 + l16;
        float bv = eb2[e * HD + h];
#pragma unroll
        for (int i = 0; i < 4; ++i) {
            int local = mt * 128 + wm * 64 + i * 16 + quad * 4;
#pragma unroll
            for (int r = 0; r < 4; ++r)
                if (local + r < n_e) {
                    int t = lists[e * T_TOK + local + r];
                    atomicAdd(&out[(size_t)t * HD + h], acc[i][j][r] + bv);
                }
        }
    }
}

// out[t][:] += routedOut[row1][:] + routedOut[row2][:]
__global__ __launch_bounds__(256) void finalize_kernel(
    const u16* __restrict__ routedOut, const int* __restrict__ pos,
    const int* __restrict__ pfx, float* __restrict__ out)
{
    const int t = blockIdx.x;
    int enc0 = pos[2 * t], enc1 = pos[2 * t + 1];
    int row0 = pfx[enc0 >> 13] + (enc0 & 8191);
    int row1 = pfx[enc1 >> 13] + (enc1 & 8191);
    int h = threadIdx.x * 4;
    ushort4 a = *(const ushort4*)(routedOut + (size_t)row0 * HD + h);
    ushort4 b = *(const ushort4*)(routedOut + (size_t)row1 * HD + h);
    float* po = out + (size_t)t * HD + h;
    float4 o = *(const float4*)po;
    o.x += bf2f(a.x) + bf2f(b.x);
    o.y += bf2f(a.y) + bf2f(b.y);
    o.z += bf2f(a.z) + bf2f(b.z);
    o.w += bf2f(a.w) + bf2f(b.w);
    *(float4*)po = o;
}

// ---------------------------------------------------------------------------
// Workspace layout (bytes):
//   wt        @ 0           : 41,943,040  (w1^T, later reused for w2^T)
//   hidS      @ 41,943,040  : 33,554,432  (bf16 [4096][2*FD])
//   hidE      @ 75,497,472  : 37,748,736  (bf16 [9216][FD])
//   xb        @ 113,246,208 :  8,388,608  (dead after gemm1)
//   routedOut @ 113,246,208 : 18,874,368  (overlays xb; lifetimes disjoint)
// primary: smalls @ 132,120,576 (cnt 64 | pfx 64 | lists 131072 | pos 32768)
//          -> total 132,284,544
// fallback: smalls @ 121,634,816 -> total 121,798,784 (proven-safe size)
// ---------------------------------------------------------------------------
extern "C" void kernel_launch(void* const* d_in, const int* in_sizes, int n_in,
                              void* d_out, int out_size, void* d_ws, size_t ws_size,
                              hipStream_t stream)
{
    (void)in_sizes; (void)n_in; (void)out_size;
    const float* x   = (const float*)d_in[0];
    const float* sw1 = (const float*)d_in[1];
    const float* sb1 = (const float*)d_in[2];
    const float* sw2 = (const float*)d_in[3];
    const float* sb2 = (const float*)d_in[4];
    const float* ew1 = (const float*)d_in[5];
    const float* eb1 = (const float*)d_in[6];
    const float* ew2 = (const float*)d_in[7];
    const float* eb2 = (const float*)d_in[8];
    const float* rw  = (const float*)d_in[9];
    const float* rb  = (const float*)d_in[10];
    float* out = (float*)d_out;

    const bool plain = (ws_size >= (size_t)132284544);
    char* ws   = (char*)d_ws;
    u16*  wt   = (u16*)ws;
    u16*  hidS = (u16*)(ws + 41943040);
    u16*  hidE = (u16*)(ws + 75497472);
    u16*  xb   = (u16*)(ws + 113246208);
    u16*  rOut = (u16*)(ws + 113246208);   // overlays xb
    size_t smallOfs = plain ? (size_t)132120576 : (size_t)121634816;
    int*  cnt   = (int*)(ws + smallOfs);
    int*  pfx   = (int*)(ws + smallOfs + 64);
    int*  lists = (int*)(ws + smallOfs + 128);
    int*  pos   = (int*)(ws + smallOfs + 128 + NEXP * T_TOK * 4);

    hipMemsetAsync(cnt, 0, 128 + (size_t)NEXP * T_TOK * 4, stream);  // cnt+pfx+lists

    router_convert_kernel<<<dim3(T_TOK / 4), dim3(256), 0, stream>>>(x, rw, rb, xb, cnt, lists, pos);
    offsets_kernel<<<dim3(1), dim3(64), 0, stream>>>(cnt, pfx);
    transpose_w1_kernel<<<dim3(FD / 32, HD / 64, NSH + NEXP), dim3(32, 8), 0, stream>>>(sw1, ew1, wt);

    gemm1_all_kernel<<<dim3(FD / 128, T_TOK / 128, NSH + NEXP), dim3(256), 0, stream>>>(
        xb, wt, sb1, eb1, cnt, pfx, lists, hidS, hidE);

    transpose_w2_kernel<<<dim3(HD / 32, FD / 64, NSH + NEXP), dim3(32, 8), 0, stream>>>(sw2, ew2, wt);

    if (plain) {
        gemm2_all_kernel<<<dim3(HD / 128, T_TOK / 128, 1 + NEXP), dim3(256), 0, stream>>>(
            hidS, hidE, wt, sb2, eb2, cnt, pfx, out, rOut);
        finalize_kernel<<<dim3(T_TOK), dim3(256), 0, stream>>>(rOut, pos, pfx, out);
    } else {
        gemm2_all_kernel<<<dim3(HD / 128, T_TOK / 128, 1), dim3(256), 0, stream>>>(
            hidS, hidE, wt, sb2, eb2, cnt, pfx, out, rOut);  // z=0 shared only
        gemm2_routed_atomic_kernel<<<dim3(HD / 128, T_TOK / 128, NEXP), dim3(256), 0, stream>>>(
            hidE, wt, eb2, cnt, pfx, lists, out);
    }
}

// Round 5
// 503.772 us; speedup vs baseline: 1.1656x; 1.0464x over previous
//
#include <hip/hip_runtime.h>
#include <hip/hip_bf16.h>

// Problem constants (fixed by setup_inputs)
#define T_TOK 4096   // B*S = 4*1024
#define HD    1024   // hidden
#define FD    2048   // ffn
#define NEXP  8
#define NSH   2

using u16 = unsigned short;
typedef __bf16 bf16x8 __attribute__((ext_vector_type(8)));
typedef float  f32x4  __attribute__((ext_vector_type(4)));
typedef u16    u16x2  __attribute__((ext_vector_type(2)));
typedef u16    u16x4  __attribute__((ext_vector_type(4)));

__device__ __forceinline__ u16 f2bf(float f) {
    __hip_bfloat16 h = __float2bfloat16(f);   // RNE
    u16 u; __builtin_memcpy(&u, &h, 2);
    return u;
}
__device__ __forceinline__ float bf2f(u16 u) {
    unsigned v = ((unsigned)u) << 16;
    float f; __builtin_memcpy(&f, &v, 4);
    return f;
}

// async global->LDS, 16B per lane. HW: wave-uniform base + lane*16B.
__device__ __forceinline__ void gl2lds16(const u16* g, u16* l) {
    __builtin_amdgcn_global_load_lds((__attribute__((address_space(1))) void*)(g),
                                     (__attribute__((address_space(3))) void*)(l),
                                     16, 0, 0);
}

// ---------------------------------------------------------------------------
// Core 128x128 tile K-loop, BK=64, 4 waves in 2x2, per k-half 4x4 16x16x32
// MFMA frags (32 MFMA/iter). Proven round-3 double-buffer semantics: stage
// next tile into buf^1 at iter top, compute buf, ONE __syncthreads per iter
// (drains stage; its target is only read next iter; the buffer it overwrote
// was last read the previous iter, protected by the previous barrier).
// BK=64 halves the number of drain events and doubles the MFMA cover per
// event vs round-3's BK=32 (25% MfmaUtil, drain-bound).
// LDS per buffer: A 128x(128B) = 16 KB + B 16 KB; 2 buffers = 64 KB.
// Bank swizzle (both-sides, rule #21): 128B rows put every row at bank 0,
// so 3-bit chunk XOR: physical 16B-chunk = logical ^ (row&7).
//   write side: pre-swizzled GLOBAL source (callers: ch =
//   ((tid&7)^((tid>>3)&7))*8 — row&7 = (lane>>3)&7 for all staged rows);
//   read side: chunk = ((kk<<2)|quad) ^ (l16&7)  (row&7 = l16&7).
// Every 8-lane read group covers all 32 banks exactly once (conflict-free).
// ---------------------------------------------------------------------------
__device__ __forceinline__ void stage8(
    const u16*& a0, const u16*& a1, const u16*& a2, const u16*& a3,
    const u16*& b0, const u16*& b1, const u16*& b2, const u16*& b3,
    u16* T, int dst0)
{
    gl2lds16(a0, T + dst0);
    gl2lds16(a1, T + dst0 + 512);      // q=1: rows +8 -> +8*64 u16
    gl2lds16(a2, T + dst0 + 1024);
    gl2lds16(a3, T + dst0 + 1536);
    gl2lds16(b0, T + 8192 + dst0);
    gl2lds16(b1, T + 8192 + dst0 + 512);
    gl2lds16(b2, T + 8192 + dst0 + 1024);
    gl2lds16(b3, T + 8192 + dst0 + 1536);
    a0 += 64; a1 += 64; a2 += 64; a3 += 64;
    b0 += 64; b1 += 64; b2 += 64; b3 += 64;
}

__device__ __forceinline__ void gemm_k_loop64(
    const u16* a0, const u16* a1, const u16* a2, const u16* a3,
    const u16* b0, const u16* b1, const u16* b2, const u16* b3,
    u16* S, int kIters, f32x4 acc[4][4])
{
    const int tid  = threadIdx.x;
    const int wave = tid >> 6, lane = tid & 63;
    const int wm = wave >> 1, wn = wave & 1;
    const int l16 = lane & 15, quad = lane >> 4;
    const int x3 = l16 & 7;                         // read-side 3-bit swizzle
    const int dst0 = (wave * 32) * 64 + lane * 8;   // u16; rows wave*32.., q=0

    stage8(a0, a1, a2, a3, b0, b1, b2, b3, S, dst0);   // t=0 -> buf0
    __syncthreads();
    for (int kt = 0; kt < kIters; ++kt) {
        u16* cur = S + (kt & 1) * 16384;
        if (kt + 1 < kIters) {
            u16* nx = S + ((kt + 1) & 1) * 16384;
            stage8(a0, a1, a2, a3, b0, b1, b2, b3, nx, dst0);
        }
        const u16* As = cur;
        const u16* Bs = cur + 8192;
#pragma unroll
        for (int kk = 0; kk < 2; ++kk) {
            bf16x8 af[4], bfv[4];
#pragma unroll
            for (int i = 0; i < 4; ++i)
                af[i] = *(const bf16x8*)(As + (wm * 64 + i * 16 + l16) * 64
                                            + ((((kk << 2) | quad) ^ x3) * 8));
#pragma unroll
            for (int j = 0; j < 4; ++j)
                bfv[j] = *(const bf16x8*)(Bs + (wn * 64 + j * 16 + l16) * 64
                                             + ((((kk << 2) | quad) ^ x3) * 8));
#pragma unroll
            for (int i = 0; i < 4; ++i)
#pragma unroll
                for (int j = 0; j < 4; ++j)
                    acc[i][j] = __builtin_amdgcn_mfma_f32_16x16x32_bf16(af[i], bfv[j], acc[i][j], 0, 0, 0);
        }
        __syncthreads();   // drains this iter's stage; next iter reads it
    }
}

// tanh-form GELU: max abs err ~1e-3 vs exact erf form — negligible after W2.
__device__ __forceinline__ float gelu_fast(float v) {
    float u = v * (0.7978845608028654f + 0.035677408136300125f * v * v);
    return v * __builtin_amdgcn_rcpf(1.0f + __expf(-2.0f * u));
}

// ---------------------------------------------------------------------------
// Coalesced bf16 epilogue: per-wave private LDS region (16 rows x stride 66).
// ---------------------------------------------------------------------------
#define EPI_STRIDE 66
template<bool GELU>
__device__ __forceinline__ void epi_store_bf16(
    f32x4 acc[4][4], const float bj[4],
    u16* __restrict__ dst, size_t ld, int rowbase, int colbase, u16* lds)
{
    const int lane = threadIdx.x & 63;
    const int l16 = lane & 15, quad = lane >> 4;
    const int rr = lane >> 2, seg = lane & 3;
#pragma unroll
    for (int i = 0; i < 4; ++i) {
#pragma unroll
        for (int j = 0; j < 4; ++j)
#pragma unroll
            for (int r = 0; r < 4; ++r) {
                float v = acc[i][j][r] + bj[j];
                if (GELU) v = gelu_fast(v);
                lds[(quad * 4 + r) * EPI_STRIDE + j * 16 + l16] = f2bf(v);
            }
        __asm__ volatile("s_waitcnt lgkmcnt(0)" ::: "memory");
        const u16* lp = lds + rr * EPI_STRIDE + seg * 16;
        u16x4 v0 = *(const u16x4*)(lp);
        u16x4 v1 = *(const u16x4*)(lp + 4);
        u16x4 v2 = *(const u16x4*)(lp + 8);
        u16x4 v3 = *(const u16x4*)(lp + 12);
        u16* gp = dst + (size_t)(rowbase + i * 16 + rr) * ld + colbase + seg * 16;
        *(u16x4*)(gp)      = v0;
        *(u16x4*)(gp + 4)  = v1;
        *(u16x4*)(gp + 8)  = v2;
        *(u16x4*)(gp + 12) = v3;
        __asm__ volatile("s_waitcnt lgkmcnt(0)" ::: "memory");  // drain reads before next i overwrites
    }
}

// ---------------------------------------------------------------------------
// T1: 2-D XCD chunk map (round 2: FETCH 322->272 MB on gemm2-shared).
// ---------------------------------------------------------------------------
template<int NX, int CX, int CY>
__device__ __forceinline__ void xcd_map2d(int& nt, int& mt) {
    const int flat = blockIdx.x + NX * blockIdx.y;
    const int xcd = flat & 7, idx = flat >> 3;
    nt = (xcd & 3) * CX + idx % CX;
    mt = (xcd >> 2) * CY + (idx / CX) % CY;
}

// ---------------------------------------------------------------------------
// Fused convert + router: writes xb (bf16) and fp32 logits top-2 per token.
// ---------------------------------------------------------------------------
__global__ __launch_bounds__(256) void router_convert_kernel(
    const float* __restrict__ x, const float* __restrict__ rw, const float* __restrict__ rb,
    u16* __restrict__ xb, int* __restrict__ cnt, int* __restrict__ lists, int* __restrict__ pos)
{
    const int t = blockIdx.x * 4 + (threadIdx.x >> 6);
    const int lane = threadIdx.x & 63;
    const float* xr = x + (size_t)t * HD;
    u16* xbr = xb + (size_t)t * HD;
    float acc[NEXP];
#pragma unroll
    for (int e = 0; e < NEXP; ++e) acc[e] = 0.f;
#pragma unroll
    for (int it = 0; it < 4; ++it) {
        int h0 = it * 256 + lane * 4;
        float4 v = *(const float4*)(xr + h0);
        ushort4 o = { f2bf(v.x), f2bf(v.y), f2bf(v.z), f2bf(v.w) };
        *(ushort4*)(xbr + h0) = o;
        float xv[4] = { v.x, v.y, v.z, v.w };
#pragma unroll
        for (int q = 0; q < 4; ++q) {
            const float4* wp = (const float4*)(rw + (size_t)(h0 + q) * NEXP);
            float4 w0 = wp[0], w1 = wp[1];
            acc[0] += xv[q] * w0.x; acc[1] += xv[q] * w0.y;
            acc[2] += xv[q] * w0.z; acc[3] += xv[q] * w0.w;
            acc[4] += xv[q] * w1.x; acc[5] += xv[q] * w1.y;
            acc[6] += xv[q] * w1.z; acc[7] += xv[q] * w1.w;
        }
    }
#pragma unroll
    for (int e = 0; e < NEXP; ++e)
        for (int off = 32; off; off >>= 1) acc[e] += __shfl_xor(acc[e], off, 64);
    if (lane == 0) {
#pragma unroll
        for (int e = 0; e < NEXP; ++e) acc[e] += rb[e];
        int b1i = 0;
        for (int e = 1; e < NEXP; ++e) if (acc[e] > acc[b1i]) b1i = e;
        int b2i = (b1i == 0) ? 1 : 0;
        for (int e = 0; e < NEXP; ++e) if (e != b1i && acc[e] > acc[b2i]) b2i = e;
        int p1 = atomicAdd(&cnt[b1i], 1); lists[b1i * T_TOK + p1] = t;
        int p2 = atomicAdd(&cnt[b2i], 1); lists[b2i * T_TOK + p2] = t;
        pos[2 * t]     = (b1i << 13) | p1;
        pos[2 * t + 1] = (b2i << 13) | p2;
    }
}

__global__ void offsets_kernel(const int* __restrict__ cnt, int* __restrict__ pfx) {
    if (threadIdx.x == 0 && blockIdx.x == 0) {
        int s = 0;
        for (int e = 0; e < NEXP; ++e) { pfx[e] = s; s += ((cnt[e] + 127) >> 7) << 7; }
        pfx[NEXP] = s;
    }
}

// ---------------------------------------------------------------------------
// Transposes: fp32 [K,N] -> bf16 [N,K]. 64(dst-contig) x 32 tiles.
// ---------------------------------------------------------------------------
__global__ __launch_bounds__(256) void transpose_w1_kernel(
    const float* __restrict__ sw1, const float* __restrict__ ew1, u16* __restrict__ wt)
{
    __shared__ u16 tile[32][65];
    const int z = blockIdx.z;
    const float* src = (z < NSH) ? (sw1 + (size_t)z * HD * FD)
                                 : (ew1 + (size_t)(z - NSH) * HD * FD);
    u16* dst = wt + (size_t)z * FD * HD;           // [f][h], ld = HD
    const int tx = threadIdx.x, ty = threadIdx.y;  // (32, 8)
    const int c0 = blockIdx.x * 32;                // over FD (dst rows)
    const int r0 = blockIdx.y * 64;                // over HD (dst contig)
#pragma unroll
    for (int k = 0; k < 8; ++k)
        tile[tx][ty + 8 * k] = f2bf(src[(size_t)(r0 + ty + 8 * k) * FD + c0 + tx]);
    __syncthreads();
#pragma unroll
    for (int k = 0; k < 4; ++k) {
        int c = ty + 8 * k;
        u16x2 v = { tile[c][2 * tx], tile[c][2 * tx + 1] };
        *(u16x2*)(dst + (size_t)(c0 + c) * HD + r0 + 2 * tx) = v;
    }
}

// shared_w2[s][f][h] -> w2tS[h][s*FD+f] (ld=2FD);  exp_w2[e][f][h] -> [e][h][f]
__global__ __launch_bounds__(256) void transpose_w2_kernel(
    const float* __restrict__ sw2, const float* __restrict__ ew2, u16* __restrict__ wt)
{
    __shared__ u16 tile[32][65];
    const int z = blockIdx.z;
    const float* src; u16* dst; size_t ldd;
    if (z < NSH) { src = sw2 + (size_t)z * FD * HD; dst = wt + (size_t)z * FD; ldd = 2 * FD; }
    else { src = ew2 + (size_t)(z - NSH) * FD * HD;
           dst = wt + (size_t)NSH * FD * HD + (size_t)(z - NSH) * HD * FD; ldd = FD; }
    const int tx = threadIdx.x, ty = threadIdx.y;  // (32, 8)
    const int c0 = blockIdx.x * 32;                // over HD (dst rows h)
    const int r0 = blockIdx.y * 64;                // over FD (dst contig f)
#pragma unroll
    for (int k = 0; k < 8; ++k)
        tile[tx][ty + 8 * k] = f2bf(src[(size_t)(r0 + ty + 8 * k) * HD + c0 + tx]);
    __syncthreads();
#pragma unroll
    for (int k = 0; k < 4; ++k) {
        int c = ty + 8 * k;
        u16x2 v = { tile[c][2 * tx], tile[c][2 * tx + 1] };
        *(u16x2*)(dst + (size_t)(c0 + c) * ldd + r0 + 2 * tx) = v;
    }
}

// ---------------------------------------------------------------------------
// GEMM1 merged: z<NSH -> shared expert s=z (hidS[t][s*FD+f]);
//               z>=NSH -> routed expert e=z-NSH (hidE[pfx[e]+slot][f]).
// ---------------------------------------------------------------------------
__global__ __launch_bounds__(256, 2) void gemm1_all_kernel(
    const u16* __restrict__ xb, const u16* __restrict__ w1t,
    const float* __restrict__ sb1, const float* __restrict__ eb1,
    const int* __restrict__ cnt, const int* __restrict__ pfx,
    const int* __restrict__ lists,
    u16* __restrict__ hidS, u16* __restrict__ hidE)
{
    const int z = blockIdx.z;
    const bool routed = (z >= NSH);
    const int e = z - NSH;
    int nt, mt;
    if (!routed) xcd_map2d<FD / 128, 4, 16>(nt, mt);          // 16x32 grid -> 4x16 chunks
    else { nt = blockIdx.x; mt = blockIdx.y; }                // B-stationary (xcd = nt%8)
    if (routed && mt * 128 >= cnt[e]) return;   // block-uniform early exit
    __shared__ __align__(16) u16 S[2 * 16384];  // 64 KB double-buffered
    const int tid = threadIdx.x, wave = tid >> 6, lane = tid & 63;
    const int rsel = wave * 32 + (lane >> 3);               // staged row, q=0
    const int ch = ((tid & 7) ^ ((tid >> 3) & 7)) * 8;      // pre-swizzled source chunk
    const u16 *a0, *a1, *a2, *a3;
    if (routed) {
        int tq[4];
#pragma unroll
        for (int q = 0; q < 4; ++q) tq[q] = lists[e * T_TOK + mt * 128 + rsel + q * 8];
        a0 = xb + (size_t)tq[0] * HD + ch;
        a1 = xb + (size_t)tq[1] * HD + ch;
        a2 = xb + (size_t)tq[2] * HD + ch;
        a3 = xb + (size_t)tq[3] * HD + ch;
    } else {
        a0 = xb + (size_t)(mt * 128 + rsel) * HD + ch;
        a1 = a0 + (size_t)8 * HD;
        a2 = a0 + (size_t)16 * HD;
        a3 = a0 + (size_t)24 * HD;
    }
    const u16* b0 = w1t + (size_t)z * FD * HD + (size_t)(nt * 128 + rsel) * HD + ch;
    const u16* b1 = b0 + (size_t)8 * HD;
    const u16* b2 = b0 + (size_t)16 * HD;
    const u16* b3 = b0 + (size_t)24 * HD;
    f32x4 acc[4][4] = {};
    gemm_k_loop64(a0, a1, a2, a3, b0, b1, b2, b3, S, HD / 64, acc);

    const int wm = wave >> 1, wn = wave & 1, l16 = lane & 15;
    const float* bias = routed ? (eb1 + e * FD) : (sb1 + z * FD);
    float bj[4];
#pragma unroll
    for (int j = 0; j < 4; ++j) bj[j] = bias[nt * 128 + wn * 64 + j * 16 + l16];
    u16* dst   = routed ? hidE : hidS;
    const size_t ld = routed ? FD : 2 * FD;
    const int rowbase = (routed ? (pfx[e] + mt * 128) : (mt * 128)) + wm * 64;
    const int colbase = (routed ? 0 : z * FD) + nt * 128 + wn * 64;
    epi_store_bf16<true>(acc, bj, dst, ld, rowbase, colbase, S + wave * 16 * EPI_STRIDE);
}

// ---------------------------------------------------------------------------
// GEMM2 merged, NO atomics: z==0 -> shared (K=4096 over both experts, plain
// fp32 stores directly to out w/ both biases); z>=1 -> routed expert e=z-1
// (K=2048, coalesced bf16 stores to routedOut[slot] w/ bias).
// ---------------------------------------------------------------------------
__global__ __launch_bounds__(256, 2) void gemm2_all_kernel(
    const u16* __restrict__ hidS, const u16* __restrict__ hidE,
    const u16* __restrict__ w2t,
    const float* __restrict__ sb2, const float* __restrict__ eb2,
    const int* __restrict__ cnt, const int* __restrict__ pfx,
    float* __restrict__ out, u16* __restrict__ routedOut)
{
    const int z = blockIdx.z;
    const int e = z - 1;
    int nt, mt;
    if (z == 0) xcd_map2d<HD / 128, 2, 16>(nt, mt);           // 8x32 grid -> 2x16 chunks
    else { nt = blockIdx.x; mt = blockIdx.y; }
    if (z >= 1 && mt * 128 >= cnt[e]) return;
    __shared__ __align__(16) u16 S[2 * 16384];
    const int tid = threadIdx.x, wave = tid >> 6, lane = tid & 63;
    const int rsel = wave * 32 + (lane >> 3);
    const int ch = ((tid & 7) ^ ((tid >> 3) & 7)) * 8;
    const int wm = wave >> 1, wn = wave & 1, l16 = lane & 15, quad = lane >> 4;
    f32x4 acc[4][4] = {};

    if (z == 0) {
        const u16* a0 = hidS + (size_t)(mt * 128 + rsel) * (2 * FD) + ch;
        const u16* a1 = a0 + (size_t)8 * (2 * FD);
        const u16* a2 = a0 + (size_t)16 * (2 * FD);
        const u16* a3 = a0 + (size_t)24 * (2 * FD);
        const u16* b0 = w2t + (size_t)(nt * 128 + rsel) * (2 * FD) + ch;
        const u16* b1 = b0 + (size_t)8 * (2 * FD);
        const u16* b2 = b0 + (size_t)16 * (2 * FD);
        const u16* b3 = b0 + (size_t)24 * (2 * FD);
        gemm_k_loop64(a0, a1, a2, a3, b0, b1, b2, b3, S, (2 * FD) / 64, acc);
#pragma unroll
        for (int j = 0; j < 4; ++j) {
            int h = nt * 128 + wn * 64 + j * 16 + l16;
            float bv = sb2[h] + sb2[HD + h];
#pragma unroll
            for (int i = 0; i < 4; ++i) {
                int row = mt * 128 + wm * 64 + i * 16 + quad * 4;
#pragma unroll
                for (int r = 0; r < 4; ++r)
                    out[(size_t)(row + r) * HD + h] = acc[i][j][r] + bv;
            }
        }
    } else {
        const int base = pfx[e];
        const u16* a0 = hidE + (size_t)(base + mt * 128 + rsel) * FD + ch;
        const u16* a1 = a0 + (size_t)8 * FD;
        const u16* a2 = a0 + (size_t)16 * FD;
        const u16* a3 = a0 + (size_t)24 * FD;
        const u16* b0 = w2t + (size_t)NSH * FD * HD + (size_t)e * HD * FD
                            + (size_t)(nt * 128 + rsel) * FD + ch;
        const u16* b1 = b0 + (size_t)8 * FD;
        const u16* b2 = b0 + (size_t)16 * FD;
        const u16* b3 = b0 + (size_t)24 * FD;
        gemm_k_loop64(a0, a1, a2, a3, b0, b1, b2, b3, S, FD / 64, acc);
        float bj[4];
#pragma unroll
        for (int j = 0; j < 4; ++j) bj[j] = eb2[e * HD + nt * 128 + wn * 64 + j * 16 + l16];
        epi_store_bf16<false>(acc, bj, routedOut, HD,
                              base + mt * 128 + wm * 64, nt * 128 + wn * 64,
                              S + wave * 16 * EPI_STRIDE);
    }
}

// Fallback (small-ws): routed scatters via atomicAdd onto out (which the
// shared pass already fully wrote). K unsplit, bias added once per (t,h,e).
__global__ __launch_bounds__(256, 2) void gemm2_routed_atomic_kernel(
    const u16* __restrict__ hidE, const u16* __restrict__ w2t,
    const float* __restrict__ eb2, const int* __restrict__ cnt,
    const int* __restrict__ pfx, const int* __restrict__ lists,
    float* __restrict__ out)
{
    const int e = blockIdx.z, nt = blockIdx.x, mt = blockIdx.y;
    const int n_e = cnt[e];
    if (mt * 128 >= n_e) return;
    __shared__ __align__(16) u16 S[2 * 16384];
    const int tid = threadIdx.x, wave = tid >> 6, lane = tid & 63;
    const int rsel = wave * 32 + (lane >> 3);
    const int ch = ((tid & 7) ^ ((tid >> 3) & 7)) * 8;
    const int base = pfx[e];
    const u16* a0 = hidE + (size_t)(base + mt * 128 + rsel) * FD + ch;
    const u16* a1 = a0 + (size_t)8 * FD;
    const u16* a2 = a0 + (size_t)16 * FD;
    const u16* a3 = a0 + (size_t)24 * FD;
    const u16* b0 = w2t + (size_t)NSH * FD * HD + (size_t)e * HD * FD
                        + (size_t)(nt * 128 + rsel) * FD + ch;
    const u16* b1 = b0 + (size_t)8 * FD;
    const u16* b2 = b0 + (size_t)16 * FD;
    const u16* b3 = b0 + (size_t)24 * FD;
    f32x4 acc[4][4] = {};
    gemm_k_loop64(a0, a1, a2, a3, b0, b1, b2, b3, S, FD / 64, acc);
    const int wm = wave >> 1, wn = wave & 1, l16 = lane & 15, quad = lane >> 4;
#pragma unroll
    for (int j = 0; j < 4; ++j) {
        int h = nt * 128 + wn * 64 + j * 16 + l16;
        float bv = eb2[e * HD + h];
#pragma unroll
        for (int i = 0; i < 4; ++i) {
            int local = mt * 128 + wm * 64 + i * 16 + quad * 4;
#pragma unroll
            for (int r = 0; r < 4; ++r)
                if (local + r < n_e) {
                    int t = lists[e * T_TOK + local + r];
                    atomicAdd(&out[(size_t)t * HD + h], acc[i][j][r] + bv);
                }
        }
    }
}

// out[t][:] += routedOut[row1][:] + routedOut[row2][:]
__global__ __launch_bounds__(256) void finalize_kernel(
    const u16* __restrict__ routedOut, const int* __restrict__ pos,
    const int* __restrict__ pfx, float* __restrict__ out)
{
    const int t = blockIdx.x;
    int enc0 = pos[2 * t], enc1 = pos[2 * t + 1];
    int row0 = pfx[enc0 >> 13] + (enc0 & 8191);
    int row1 = pfx[enc1 >> 13] + (enc1 & 8191);
    int h = threadIdx.x * 4;
    ushort4 a = *(const ushort4*)(routedOut + (size_t)row0 * HD + h);
    ushort4 b = *(const ushort4*)(routedOut + (size_t)row1 * HD + h);
    float* po = out + (size_t)t * HD + h;
    float4 o = *(const float4*)po;
    o.x += bf2f(a.x) + bf2f(b.x);
    o.y += bf2f(a.y) + bf2f(b.y);
    o.z += bf2f(a.z) + bf2f(b.z);
    o.w += bf2f(a.w) + bf2f(b.w);
    *(float4*)po = o;
}

// ---------------------------------------------------------------------------
// Workspace layout (bytes):
//   wt        @ 0           : 41,943,040  (w1^T, later reused for w2^T)
//   hidS      @ 41,943,040  : 33,554,432  (bf16 [4096][2*FD])
//   hidE      @ 75,497,472  : 37,748,736  (bf16 [9216][FD])
//   xb        @ 113,246,208 :  8,388,608  (dead after gemm1)
//   routedOut @ 113,246,208 : 18,874,368  (overlays xb; lifetimes disjoint)
// primary: smalls @ 132,120,576 (cnt 64 | pfx 64 | lists 131072 | pos 32768)
//          -> total 132,284,544
// fallback: smalls @ 121,634,816 -> total 121,798,784 (proven-safe size)
// ---------------------------------------------------------------------------
extern "C" void kernel_launch(void* const* d_in, const int* in_sizes, int n_in,
                              void* d_out, int out_size, void* d_ws, size_t ws_size,
                              hipStream_t stream)
{
    (void)in_sizes; (void)n_in; (void)out_size;
    const float* x   = (const float*)d_in[0];
    const float* sw1 = (const float*)d_in[1];
    const float* sb1 = (const float*)d_in[2];
    const float* sw2 = (const float*)d_in[3];
    const float* sb2 = (const float*)d_in[4];
    const float* ew1 = (const float*)d_in[5];
    const float* eb1 = (const float*)d_in[6];
    const float* ew2 = (const float*)d_in[7];
    const float* eb2 = (const float*)d_in[8];
    const float* rw  = (const float*)d_in[9];
    const float* rb  = (const float*)d_in[10];
    float* out = (float*)d_out;

    const bool plain = (ws_size >= (size_t)132284544);
    char* ws   = (char*)d_ws;
    u16*  wt   = (u16*)ws;
    u16*  hidS = (u16*)(ws + 41943040);
    u16*  hidE = (u16*)(ws + 75497472);
    u16*  xb   = (u16*)(ws + 113246208);
    u16*  rOut = (u16*)(ws + 113246208);   // overlays xb
    size_t smallOfs = plain ? (size_t)132120576 : (size_t)121634816;
    int*  cnt   = (int*)(ws + smallOfs);
    int*  pfx   = (int*)(ws + smallOfs + 64);
    int*  lists = (int*)(ws + smallOfs + 128);
    int*  pos   = (int*)(ws + smallOfs + 128 + NEXP * T_TOK * 4);

    hipMemsetAsync(cnt, 0, 128 + (size_t)NEXP * T_TOK * 4, stream);  // cnt+pfx+lists

    router_convert_kernel<<<dim3(T_TOK / 4), dim3(256), 0, stream>>>(x, rw, rb, xb, cnt, lists, pos);
    offsets_kernel<<<dim3(1), dim3(64), 0, stream>>>(cnt, pfx);
    transpose_w1_kernel<<<dim3(FD / 32, HD / 64, NSH + NEXP), dim3(32, 8), 0, stream>>>(sw1, ew1, wt);

    gemm1_all_kernel<<<dim3(FD / 128, T_TOK / 128, NSH + NEXP), dim3(256), 0, stream>>>(
        xb, wt, sb1, eb1, cnt, pfx, lists, hidS, hidE);

    transpose_w2_kernel<<<dim3(HD / 32, FD / 64, NSH + NEXP), dim3(32, 8), 0, stream>>>(sw2, ew2, wt);

    if (plain) {
        gemm2_all_kernel<<<dim3(HD / 128, T_TOK / 128, 1 + NEXP), dim3(256), 0, stream>>>(
            hidS, hidE, wt, sb2, eb2, cnt, pfx, out, rOut);
        finalize_kernel<<<dim3(T_TOK), dim3(256), 0, stream>>>(rOut, pos, pfx, out);
    } else {
        gemm2_all_kernel<<<dim3(HD / 128, T_TOK / 128, 1), dim3(256), 0, stream>>>(
            hidS, hidE, wt, sb2, eb2, cnt, pfx, out, rOut);  // z=0 shared only
        gemm2_routed_atomic_kernel<<<dim3(HD / 128, T_TOK / 128, NEXP), dim3(256), 0, stream>>>(
            hidE, wt, eb2, cnt, pfx, lists, out);
    }
}